// Round 7
// baseline (1133.938 us; speedup 1.0000x reference)
//
#include <hip/hip_runtime.h>
#include <cstddef>

// Problem constants
#define BB 32
#define PP 196
#define DENC 256
#define EE 512
#define HH 512
#define AA 256
#define VV 30000
#define TT 20
#define BH (BB*HH)          // 16384
#define G4 (4*HH)           // 2048
#define VPAD 30080          // VV padded to multiple of 64
#define NBLK 256            // persistent-kernel grid (one block per CU)
#define NFLAGS 9216         // (32 cflag + 256 gflag) slots x 32 uints (128B pad)

typedef __attribute__((ext_vector_type(8))) short short8;
typedef __attribute__((ext_vector_type(4))) float f32x4;

__device__ __forceinline__ float fast_sigmoid(float x) {
    return 1.f / (1.f + __expf(-x));
}
__device__ __forceinline__ float fast_tanh(float x) {
    x = fminf(fmaxf(x, -15.f), 15.f);
    float e = __expf(2.f * x);
    return (e - 1.f) / (e + 1.f);
}
// truncation split: hi = bf16_trunc(x), lo = bf16_trunc(x - hi)
__device__ __forceinline__ void split_bf16(float x, unsigned short& hi, unsigned short& lo) {
    const unsigned u = __float_as_uint(x);
    hi = (unsigned short)(u >> 16);
    const float r = x - __uint_as_float(u & 0xffff0000u);
    lo = (unsigned short)(__float_as_uint(r) >> 16);
}

// Agent-scope coherent load (bypasses the non-coherent per-XCD L2; reads the
// coherent point). Used ONLY for the small cross-block payload (ctxb, hbuf).
__device__ __forceinline__ float aload(const float* p) {
    const unsigned u = __hip_atomic_load((const unsigned*)p, __ATOMIC_RELAXED,
                                         __HIP_MEMORY_SCOPE_AGENT);
    return __uint_as_float(u);
}

// Relaxed spin on a per-producer flag slot (distinct cacheline per producer).
__device__ __forceinline__ void wait_flag(const unsigned* f, unsigned target) {
    while (__hip_atomic_load(f, __ATOMIC_RELAXED, __HIP_MEMORY_SCOPE_AGENT) < target) {
        __builtin_amdgcn_s_sleep(2);
    }
}

// ---------------------------------------------------------------------------
// att1[b,p,a] = enc[b,p,:] @ W_enc_att[:,a] + b_enc_att[a]
// (block 0 also zeroes the flag slots for the fused kernel — per-launch reset)
// ---------------------------------------------------------------------------
__global__ void att1_kernel(const float* __restrict__ enc,
                            const float* __restrict__ W,
                            const float* __restrict__ bias,
                            float* __restrict__ att1,
                            unsigned* __restrict__ flags) {
    const int tid = threadIdx.x;
    if (blockIdx.x == 0) {
        for (int i = tid; i < NFLAGS; i += 256)
            __hip_atomic_store(flags + i, 0u, __ATOMIC_RELAXED, __HIP_MEMORY_SCOPE_AGENT);
    }
    __shared__ float xs[8][DENC];
    const int r0 = blockIdx.x * 8;
    #pragma unroll
    for (int bi = 0; bi < 8; ++bi)
        xs[bi][tid] = enc[(size_t)(r0 + bi) * DENC + tid];
    __syncthreads();
    float acc[8];
    const float bv = bias[tid];
    #pragma unroll
    for (int bi = 0; bi < 8; ++bi) acc[bi] = bv;
    #pragma unroll 8
    for (int k = 0; k < DENC; ++k) {
        const float w = W[k * AA + tid];
        #pragma unroll
        for (int bi = 0; bi < 8; ++bi) acc[bi] += xs[bi][k] * w;
    }
    #pragma unroll
    for (int bi = 0; bi < 8; ++bi)
        att1[(size_t)(r0 + bi) * AA + tid] = acc[bi];
}

// ---------------------------------------------------------------------------
// Epre[m, j] = emb[captions[b,t]] @ W_ih[0:512, j] + b_ih[j] + b_hh[j]
// ---------------------------------------------------------------------------
__global__ void epre_kernel(const int* __restrict__ captions,
                            const float* __restrict__ emb,
                            const float* __restrict__ Wih,
                            const float* __restrict__ bih,
                            const float* __restrict__ bhh,
                            float* __restrict__ Epre) {
    __shared__ float xs[8][EE];
    const int tid = threadIdx.x;
    const int jc = blockIdx.x;     // 0..7
    const int mg = blockIdx.y;     // 0..79
    const int j = jc * 256 + tid;

    #pragma unroll
    for (int i = 0; i < 8; ++i) {
        const int m = mg * 8 + i;
        const int t = m >> 5, b = m & 31;
        const int cap = captions[b * TT + t];
        const float* erow = emb + (size_t)cap * EE;
        xs[i][tid]       = erow[tid];
        xs[i][tid + 256] = erow[tid + 256];
    }
    __syncthreads();

    float acc[8];
    const float bv = bih[j] + bhh[j];
    #pragma unroll
    for (int i = 0; i < 8; ++i) acc[i] = bv;
    #pragma unroll 8
    for (int k = 0; k < EE; ++k) {
        const float w = Wih[(size_t)k * G4 + j];
        #pragma unroll
        for (int i = 0; i < 8; ++i) acc[i] += xs[i][k] * w;
    }
    #pragma unroll
    for (int i = 0; i < 8; ++i)
        Epre[(size_t)(mg * 8 + i) * G4 + j] = acc[i];
}

// ---------------------------------------------------------------------------
// One-time weight repack for the fused gates GEMM.
// Wpk[jc][k][cl] = (k < 256) ? Wih[512+k][col] : Whh[k-256][col]
//   where col = (cl>>4)*512 + jc*16 + (cl&15),  jc=0..31, k=0..767, cl=0..63.
// Turns the per-block 64-col slice (stride-8KB -> L2-set thrash) into a
// contiguous 196KB stream that stays L2-resident across all 20 steps.
// ---------------------------------------------------------------------------
__global__ void pack_w_kernel(const float* __restrict__ Wih,
                              const float* __restrict__ Whh,
                              float* __restrict__ Wpk) {
    const int jc = blockIdx.x;     // 0..31
    const int tid = threadIdx.x;   // 0..255
    float* dst = Wpk + (size_t)jc * 768 * 64;
    for (int i = tid; i < 768 * 64; i += 256) {
        const int k = i >> 6, cl = i & 63;
        const int col = ((cl >> 4) * 512) + jc * 16 + (cl & 15);
        const float v = (k < 256) ? Wih[(size_t)(512 + k) * G4 + col]
                                  : Whh[(size_t)(k - 256) * G4 + col];
        dst[i] = v;
    }
}

// ---------------------------------------------------------------------------
// FUSED persistent time-loop kernel: 256 blocks x 1024 threads, cooperative.
// Sync via per-block flags; payload reads use agent-coherent loads (aload),
// so NO cache-invalidating fences appear anywhere in the loop.
//   cflag[b]   (b=0..31) : attention block b publishes ctxb(t)  -> value t+1
//   gflag[bid] (0..255)  : gates block publishes its h(t) slice -> value t+1
// Gates GEMM reads the packed Wpk slice (contiguous, L2-resident).
// ---------------------------------------------------------------------------
__global__ __launch_bounds__(1024) void fused_loop_kernel(
        const float* __restrict__ att1,
        const float* __restrict__ enc,
        const float* __restrict__ Wda,
        const float* __restrict__ bda,
        const float* __restrict__ Wfull,
        const float* __restrict__ bfull,
        const float* __restrict__ Wpk,
        const float* __restrict__ Epre,
        float* __restrict__ hbuf,        // [2][32][512]
        float* __restrict__ ctxb,        // [32][256]
        float* __restrict__ Hall,        // [640][512]
        unsigned short* __restrict__ Ah,
        unsigned short* __restrict__ Al,
        unsigned* flags,
        int write_split) {
    const int bid = blockIdx.x;        // 0..255
    const int tid = threadIdx.x;       // 0..1023
    const int jc = bid & 31;           // h-dim slice
    const int bg = bid >> 5;           // 0..7 (4 batches each)

    unsigned* cflag = flags;           // [32] slots, stride 32 uints (128B)
    unsigned* gflag = flags + 32 * 32; // [256] slots, stride 32 uints

    __shared__ float h_s[HH];
    __shared__ float part[4][256];
    __shared__ float att2_s[AA];
    __shared__ float e_s[256];
    __shared__ float red_s[256];
    __shared__ float xs[4][768];
    __shared__ float gred[256];

    float c_reg = 0.f;                 // per-thread c state (threads tid<64 use it)

    for (int t = 0; t < TT; ++t) {
        const float* hprev = hbuf + ((t + 1) & 1) * 16384;   // h(t-1)

        // ---------------- attention phase (blocks 0..31) ----------------
        if (bid < 32) {
            const int b = bid;
            if (t > 0) {
                // wait for h(t-1)[b] = all 32 gates blocks of group b>>2
                if (tid < 32) wait_flag(gflag + ((b >> 2) * 32 + tid) * 32, (unsigned)t);
                asm volatile("" ::: "memory");
                __syncthreads();
            }
            if (tid < 512) h_s[tid] = (t == 0) ? 0.f : aload(&hprev[b * HH + tid]);
            __syncthreads();
            // att2 = h @ Wda + bda (4-way split-K)
            {
                const int q = tid >> 8, col = tid & 255;
                const float* W = Wda + (size_t)(q * 128) * AA + col;
                const float* hh = h_s + q * 128;
                float acc = 0.f;
                #pragma unroll 16
                for (int k = 0; k < 128; ++k) acc += hh[k] * W[(size_t)k * AA];
                part[q][col] = acc;
            }
            __syncthreads();
            if (tid < 256)
                att2_s[tid] = part[0][tid] + part[1][tid] + part[2][tid] + part[3][tid] + bda[tid];
            __syncthreads();
            // e[p], one wave per p
            {
                const int wave = tid >> 6, lane = tid & 63;
                const float bf0 = bfull[0];
                for (int p = wave; p < PP; p += 16) {
                    const float* row = att1 + ((size_t)b * PP + p) * AA;
                    float s = 0.f;
                    #pragma unroll
                    for (int q = 0; q < 4; ++q) {
                        const int a = lane + q * 64;
                        s += fast_tanh(row[a] + att2_s[a]) * Wfull[a];
                    }
                    #pragma unroll
                    for (int off = 32; off > 0; off >>= 1) s += __shfl_down(s, off, 64);
                    if (lane == 0) e_s[p] = s + bf0;
                }
            }
            __syncthreads();
            // softmax over p
            const float val = (tid < PP) ? e_s[tid] : -3.4e38f;
            if (tid < 256) red_s[tid] = val;
            __syncthreads();
            #pragma unroll
            for (int s = 128; s > 0; s >>= 1) {
                if (tid < s) red_s[tid] = fmaxf(red_s[tid], red_s[tid + s]);
                __syncthreads();
            }
            const float mx = red_s[0];
            __syncthreads();
            const float ex = (tid < PP) ? __expf(val - mx) : 0.f;
            if (tid < 256) red_s[tid] = ex;
            __syncthreads();
            #pragma unroll
            for (int s = 128; s > 0; s >>= 1) {
                if (tid < s) red_s[tid] += red_s[tid + s];
                __syncthreads();
            }
            const float inv = 1.f / red_s[0];
            __syncthreads();
            if (tid < 256) e_s[tid] = ex * inv;   // alpha
            __syncthreads();
            // context = alpha @ enc
            {
                const int q = tid >> 8, col = tid & 255;
                const float* erow = enc + (size_t)b * PP * DENC + col;
                float acc = 0.f;
                const int p0 = q * 49;
                #pragma unroll 7
                for (int p = p0; p < p0 + 49; ++p) acc += e_s[p] * erow[(size_t)p * DENC];
                part[q][col] = acc;
            }
            __syncthreads();
            if (tid < 256)
                ctxb[b * DENC + tid] = part[0][tid] + part[1][tid] + part[2][tid] + part[3][tid];
            __syncthreads();
            if (tid == 0)
                __hip_atomic_store(cflag + b * 32, (unsigned)(t + 1),
                                   __ATOMIC_RELEASE, __HIP_MEMORY_SCOPE_AGENT);
        }

        // ---------------- gates + pointwise phase (all blocks) ----------------
        // wait for ctxb of this block's 4 batches
        if (tid < 4) wait_flag(cflag + (bg * 4 + tid) * 32, (unsigned)(t + 1));
        asm volatile("" ::: "memory");
        __syncthreads();

        // stage x = [context(256), h(512)] for 4 batches (coherent loads)
        #pragma unroll
        for (int ii = 0; ii < 3; ++ii) {
            const int idx = tid + ii * 1024;
            const int bi = idx / 768;
            const int k = idx - bi * 768;
            const int b = bg * 4 + bi;
            xs[bi][k] = (k < 256) ? aload(&ctxb[b * DENC + k])
                                  : ((t > 0) ? aload(&hprev[b * HH + (k - 256)]) : 0.f);
        }
        __syncthreads();
        {
            const int kq = tid >> 8;            // 0..3, wave-uniform
            const int r = tid & 255;
            const int bl = r >> 6;              // local batch 0..3
            const int cl = r & 63;              // g*16 + hdl
            const float* xr = xs[bl] + kq * 192;
            const float* Wp = Wpk + ((size_t)jc * 768 + kq * 192) * 64 + cl;
            float acc = 0.f;
            #pragma unroll 16
            for (int k = 0; k < 192; ++k) acc += xr[k] * Wp[(size_t)k * 64];
            part[kq][r] = acc;
        }
        __syncthreads();
        if (tid < 256) {
            const int bl = tid >> 6;
            const int cl = tid & 63;
            const int b = bg * 4 + bl;
            const int col = ((cl >> 4) * 512) + jc * 16 + (cl & 15);
            gred[tid] = part[0][tid] + part[1][tid] + part[2][tid] + part[3][tid]
                      + Epre[(size_t)(t * BB + b) * G4 + col];
        }
        __syncthreads();
        if (tid < 64) {
            const int bl = tid >> 4;            // 0..3
            const int hdl = tid & 15;
            const float gi = gred[bl * 64 +  0 + hdl];
            const float gf = gred[bl * 64 + 16 + hdl];
            const float gg = gred[bl * 64 + 32 + hdl];
            const float go = gred[bl * 64 + 48 + hdl];
            const float cn = fast_sigmoid(gf) * c_reg + fast_sigmoid(gi) * fast_tanh(gg);
            const float hn = fast_sigmoid(go) * fast_tanh(cn);
            c_reg = cn;
            const int b = bg * 4 + bl;
            const int hd = jc * 16 + hdl;
            hbuf[(t & 1) * 16384 + b * HH + hd] = hn;
            const size_t mi = (size_t)(t * BB + b) * HH + hd;
            Hall[mi] = hn;
            if (write_split) {
                unsigned short hh_, ll_;
                split_bf16(hn, hh_, ll_);
                Ah[mi] = hh_;
                Al[mi] = ll_;
            }
        }
        if (t < TT - 1) {
            __syncthreads();
            if (tid == 0)
                __hip_atomic_store(gflag + bid * 32, (unsigned)(t + 1),
                                   __ATOMIC_RELEASE, __HIP_MEMORY_SCOPE_AGENT);
        }
    }
}

// ---------------------------------------------------------------------------
// FALLBACK per-timestep kernels (used only if cooperative launch fails)
// ---------------------------------------------------------------------------
__global__ __launch_bounds__(1024) void attn_step_kernel(
        int t,
        const float* __restrict__ att1,
        const float* __restrict__ enc,
        float* __restrict__ Hall,
        float* __restrict__ cbuf,
        const float* __restrict__ gates,
        float* __restrict__ context,
        const float* __restrict__ Wda,
        const float* __restrict__ bda,
        const float* __restrict__ Wfull,
        const float* __restrict__ bfull) {
    __shared__ float h_s[HH];
    __shared__ float part[4][256];
    __shared__ float att2_s[AA];
    __shared__ float e_s[256];
    __shared__ float red_s[256];
    const int b = blockIdx.x;
    const int tid = threadIdx.x;

    if (tid < 512) {
        if (t == 0) {
            h_s[tid] = 0.f;
            cbuf[b * HH + tid] = 0.f;
        } else {
            const float* g = gates + b * G4;
            const float gi = g[tid];
            const float gf = g[HH + tid];
            const float gg = g[2 * HH + tid];
            const float go = g[3 * HH + tid];
            const float cp = cbuf[b * HH + tid];
            const float cn = fast_sigmoid(gf) * cp + fast_sigmoid(gi) * fast_tanh(gg);
            const float hn = fast_sigmoid(go) * fast_tanh(cn);
            cbuf[b * HH + tid] = cn;
            Hall[(size_t)(t - 1) * BH + b * HH + tid] = hn;
            h_s[tid] = hn;
        }
    }
    __syncthreads();

    {
        const int q = tid >> 8, col = tid & 255;
        const float* W = Wda + (size_t)(q * 128) * AA + col;
        const float* hh = h_s + q * 128;
        float acc = 0.f;
        #pragma unroll 16
        for (int k = 0; k < 128; ++k) acc += hh[k] * W[(size_t)k * AA];
        part[q][col] = acc;
    }
    __syncthreads();
    if (tid < 256)
        att2_s[tid] = part[0][tid] + part[1][tid] + part[2][tid] + part[3][tid] + bda[tid];
    __syncthreads();

    {
        const int wave = tid >> 6, lane = tid & 63;
        const float bf0 = bfull[0];
        for (int p = wave; p < PP; p += 16) {
            const float* row = att1 + ((size_t)b * PP + p) * AA;
            float s = 0.f;
            #pragma unroll
            for (int q = 0; q < 4; ++q) {
                const int a = lane + q * 64;
                s += fast_tanh(row[a] + att2_s[a]) * Wfull[a];
            }
            #pragma unroll
            for (int off = 32; off > 0; off >>= 1) s += __shfl_down(s, off, 64);
            if (lane == 0) e_s[p] = s + bf0;
        }
    }
    __syncthreads();

    const float val = (tid < PP) ? e_s[tid] : -3.4e38f;
    if (tid < 256) red_s[tid] = val;
    __syncthreads();
    #pragma unroll
    for (int s = 128; s > 0; s >>= 1) {
        if (tid < s) red_s[tid] = fmaxf(red_s[tid], red_s[tid + s]);
        __syncthreads();
    }
    const float mx = red_s[0];
    __syncthreads();
    const float ex = (tid < PP) ? __expf(val - mx) : 0.f;
    if (tid < 256) red_s[tid] = ex;
    __syncthreads();
    #pragma unroll
    for (int s = 128; s > 0; s >>= 1) {
        if (tid < s) red_s[tid] += red_s[tid + s];
        __syncthreads();
    }
    const float inv = 1.f / red_s[0];
    __syncthreads();
    if (tid < 256) e_s[tid] = ex * inv;
    __syncthreads();

    {
        const int q = tid >> 8, col = tid & 255;
        const float* erow = enc + (size_t)b * PP * DENC + col;
        float acc = 0.f;
        const int p0 = q * 49;
        #pragma unroll 7
        for (int p = p0; p < p0 + 49; ++p) acc += e_s[p] * erow[(size_t)p * DENC];
        part[q][col] = acc;
    }
    __syncthreads();
    if (tid < 256)
        context[b * DENC + tid] = part[0][tid] + part[1][tid] + part[2][tid] + part[3][tid];
}

__global__ __launch_bounds__(1024) void gates_kernel(
        int t,
        const float* __restrict__ context,
        const float* __restrict__ Hall,
        const float* __restrict__ Epre,
        const float* __restrict__ Wih,
        const float* __restrict__ Whh,
        float* __restrict__ gates) {
    __shared__ float xs[4][768];
    __shared__ float part[4][256];
    const int tid = threadIdx.x;
    const int jc = blockIdx.x;
    const int bg = blockIdx.y;

    for (int idx = tid; idx < 4 * 768; idx += 1024) {
        const int bi = idx / 768;
        const int k = idx - bi * 768;
        const int b = bg * 4 + bi;
        float v;
        if (k < 256) v = context[b * DENC + k];
        else v = (t > 0) ? Hall[(size_t)(t - 1) * BH + b * HH + (k - 256)] : 0.f;
        xs[bi][k] = v;
    }
    __syncthreads();

    const int kq = tid >> 8;
    const int r = tid & 255;
    const int jl = r & 63, bl = r >> 6;
    const int j = jc * 64 + jl;
    const float* xrow = xs[bl];

    float acc = 0.f;
    if (kq == 0) {
        const float* W1 = Wih + (size_t)512 * G4 + j;
        #pragma unroll 16
        for (int k = 0; k < 192; ++k) acc += xrow[k] * W1[(size_t)k * G4];
    } else if (kq == 1) {
        const float* W1 = Wih + (size_t)704 * G4 + j;
        #pragma unroll 16
        for (int k = 0; k < 64; ++k) acc += xrow[192 + k] * W1[(size_t)k * G4];
        const float* W2 = Whh + j;
        #pragma unroll 16
        for (int k = 0; k < 128; ++k) acc += xrow[256 + k] * W2[(size_t)k * G4];
    } else if (kq == 2) {
        const float* W2 = Whh + (size_t)128 * G4 + j;
        #pragma unroll 16
        for (int k = 0; k < 192; ++k) acc += xrow[384 + k] * W2[(size_t)k * G4];
    } else {
        const float* W2 = Whh + (size_t)320 * G4 + j;
        #pragma unroll 16
        for (int k = 0; k < 192; ++k) acc += xrow[576 + k] * W2[(size_t)k * G4];
    }
    part[kq][r] = acc;
    __syncthreads();

    if (tid < 256) {
        const int b = bg * 4 + bl;
        gates[(size_t)b * G4 + j] = part[0][tid] + part[1][tid] + part[2][tid] + part[3][tid]
                                  + Epre[(size_t)(t * BB + b) * G4 + j];
    }
}

__global__ void final_update_kernel(const float* __restrict__ gates,
                                    const float* __restrict__ cbuf,
                                    float* __restrict__ Hall) {
    const int idx = blockIdx.x * 256 + threadIdx.x;
    const int b = idx >> 9, hi = idx & 511;
    const float* g = gates + b * G4;
    const float gi = g[hi];
    const float gf = g[HH + hi];
    const float gg = g[2 * HH + hi];
    const float go = g[3 * HH + hi];
    const float cp = cbuf[idx];
    const float cn = fast_sigmoid(gf) * cp + fast_sigmoid(gi) * fast_tanh(gg);
    const float hn = fast_sigmoid(go) * fast_tanh(cn);
    Hall[(size_t)(TT - 1) * BH + idx] = hn;
}

__global__ void split_hall_kernel(const float* __restrict__ Hall,
                                  unsigned short* __restrict__ Ah,
                                  unsigned short* __restrict__ Al) {
    const int idx = blockIdx.x * 256 + threadIdx.x;
    unsigned short h, l;
    split_bf16(Hall[idx], h, l);
    Ah[idx] = h; Al[idx] = l;
}

// ---------------------------------------------------------------------------
// Transpose + split Wfc[k][v] -> Wt_h/Wt_l[v][k], v padded to VPAD (zero-fill).
// ---------------------------------------------------------------------------
__global__ void split_wfc_kernel(const float* __restrict__ Wfc,
                                 unsigned short* __restrict__ Wt_h,
                                 unsigned short* __restrict__ Wt_l) {
    __shared__ unsigned short th[64][66];
    __shared__ unsigned short tl[64][66];
    const int tid = threadIdx.x;
    const int k0 = blockIdx.x * 64;
    const int v0 = blockIdx.y * 64;

    const int c = tid & 63, r0 = tid >> 6;
    #pragma unroll
    for (int i = 0; i < 16; ++i) {
        const int r = r0 + i * 4;
        const int v = v0 + c;
        const float x = (v < VV) ? Wfc[(size_t)(k0 + r) * VV + v] : 0.f;
        unsigned short h, l;
        split_bf16(x, h, l);
        th[r][c] = h; tl[r][c] = l;
    }
    __syncthreads();

    const int v = tid >> 2, q = tid & 3;
    short8 oh0, oh1, ol0, ol1;
    #pragma unroll
    for (int i = 0; i < 8; ++i) {
        oh0[i] = (short)th[q * 16 + i][v];
        oh1[i] = (short)th[q * 16 + 8 + i][v];
        ol0[i] = (short)tl[q * 16 + i][v];
        ol1[i] = (short)tl[q * 16 + 8 + i][v];
    }
    unsigned short* dh = Wt_h + (size_t)(v0 + v) * HH + k0 + q * 16;
    unsigned short* dl = Wt_l + (size_t)(v0 + v) * HH + k0 + q * 16;
    *(short8*)(dh) = oh0; *(short8*)(dh + 8) = oh1;
    *(short8*)(dl) = ol0; *(short8*)(dl + 8) = ol1;
}

// ---------------------------------------------------------------------------
// Output projection, pre-split path: pure-copy staging, bf16x3 MFMA.
// ---------------------------------------------------------------------------
#define LDK 40   // padded LDS row length in bf16 units

__global__ __launch_bounds__(256) void gemm_out_mfma_pre(
        const unsigned short* __restrict__ Ah,
        const unsigned short* __restrict__ Al,
        const unsigned short* __restrict__ Wt_h,
        const unsigned short* __restrict__ Wt_l,
        const float* __restrict__ bfc,
        float* __restrict__ out) {
    __shared__ unsigned short As_h[128 * LDK];
    __shared__ unsigned short As_l[128 * LDK];
    __shared__ unsigned short Bs_h[128 * LDK];
    __shared__ unsigned short Bs_l[128 * LDK];

    const int tid = threadIdx.x;
    const int m0 = blockIdx.x * 128;
    const int v0 = blockIdx.y * 128;

    const int wave = tid >> 6, lane = tid & 63;
    const int wm = wave & 1, wn = wave >> 1;
    const int row16 = lane & 15, quad = lane >> 4;

    const int sn = tid & 127;
    const int skq = tid >> 7;

    f32x4 acc[4][4] = {};

    #pragma unroll 1
    for (int k0 = 0; k0 < HH; k0 += 32) {
        {
            const size_t src = (size_t)(m0 + sn) * HH + k0 + skq * 16;
            const short8 h0 = *(const short8*)(Ah + src);
            const short8 h1 = *(const short8*)(Ah + src + 8);
            const short8 l0 = *(const short8*)(Al + src);
            const short8 l1 = *(const short8*)(Al + src + 8);
            unsigned short* dh = &As_h[sn * LDK + skq * 16];
            unsigned short* dl = &As_l[sn * LDK + skq * 16];
            *(short8*)(dh) = h0; *(short8*)(dh + 8) = h1;
            *(short8*)(dl) = l0; *(short8*)(dl + 8) = l1;
        }
        {
            const size_t src = (size_t)(v0 + sn) * HH + k0 + skq * 16;
            const short8 h0 = *(const short8*)(Wt_h + src);
            const short8 h1 = *(const short8*)(Wt_h + src + 8);
            const short8 l0 = *(const short8*)(Wt_l + src);
            const short8 l1 = *(const short8*)(Wt_l + src + 8);
            unsigned short* dh = &Bs_h[sn * LDK + skq * 16];
            unsigned short* dl = &Bs_l[sn * LDK + skq * 16];
            *(short8*)(dh) = h0; *(short8*)(dh + 8) = h1;
            *(short8*)(dl) = l0; *(short8*)(dl + 8) = l1;
        }
        __syncthreads();

        short8 ah[4], al[4], bh[4], bl[4];
        #pragma unroll
        for (int mi = 0; mi < 4; ++mi) {
            const int off = (wm * 64 + mi * 16 + row16) * LDK + quad * 8;
            ah[mi] = *(const short8*)&As_h[off];
            al[mi] = *(const short8*)&As_l[off];
        }
        #pragma unroll
        for (int ni = 0; ni < 4; ++ni) {
            const int off = (wn * 64 + ni * 16 + row16) * LDK + quad * 8;
            bh[ni] = *(const short8*)&Bs_h[off];
            bl[ni] = *(const short8*)&Bs_l[off];
        }
        #pragma unroll
        for (int mi = 0; mi < 4; ++mi) {
            #pragma unroll
            for (int ni = 0; ni < 4; ++ni) {
                acc[mi][ni] = __builtin_amdgcn_mfma_f32_16x16x32_bf16(
                    ah[mi], bh[ni], acc[mi][ni], 0, 0, 0);
                acc[mi][ni] = __builtin_amdgcn_mfma_f32_16x16x32_bf16(
                    ah[mi], bl[ni], acc[mi][ni], 0, 0, 0);
                acc[mi][ni] = __builtin_amdgcn_mfma_f32_16x16x32_bf16(
                    al[mi], bh[ni], acc[mi][ni], 0, 0, 0);
            }
        }
        __syncthreads();
    }

    #pragma unroll
    for (int ni = 0; ni < 4; ++ni) {
        const int v = v0 + wn * 64 + ni * 16 + row16;
        if (v >= VV) continue;
        const float bias = bfc[v];
        #pragma unroll
        for (int mi = 0; mi < 4; ++mi) {
            const int mbase = m0 + wm * 64 + mi * 16 + quad * 4;
            #pragma unroll
            for (int r = 0; r < 4; ++r) {
                const int m = mbase + r;
                const int t_idx = m >> 5;
                const int b_idx = m & 31;
                out[((size_t)b_idx * TT + t_idx) * VV + v] = acc[mi][ni][r] + bias;
            }
        }
    }
}

// ---------------------------------------------------------------------------
// Fallback gemm (in-kernel split) — used when ws is too small for tables.
// ---------------------------------------------------------------------------
__global__ __launch_bounds__(256) void gemm_out_mfma_fb(
        const float* __restrict__ Hall,
        const float* __restrict__ Wfc,
        const float* __restrict__ bfc,
        float* __restrict__ out) {
    __shared__ unsigned short As_h[128 * LDK];
    __shared__ unsigned short As_l[128 * LDK];
    __shared__ unsigned short Bs_h[128 * LDK];
    __shared__ unsigned short Bs_l[128 * LDK];

    const int tid = threadIdx.x;
    const int m0 = blockIdx.x * 128;
    const int v0 = blockIdx.y * 128;

    const int wave = tid >> 6, lane = tid & 63;
    const int wm = wave & 1, wn = wave >> 1;
    const int row16 = lane & 15, quad = lane >> 4;

    const int sn = tid & 127;
    const int skq = tid >> 7;

    f32x4 acc[4][4] = {};

    #pragma unroll 1
    for (int k0 = 0; k0 < HH; k0 += 32) {
        {
            const float* asrc = Hall + (size_t)(m0 + sn) * HH + k0 + skq * 16;
            short8 h0, h1, l0, l1;
            #pragma unroll
            for (int i = 0; i < 16; i += 4) {
                const float4 v = *reinterpret_cast<const float4*>(asrc + i);
                const float vv[4] = {v.x, v.y, v.z, v.w};
                #pragma unroll
                for (int jj = 0; jj < 4; ++jj) {
                    unsigned short hb, lb;
                    split_bf16(vv[jj], hb, lb);
                    const int e = i + jj;
                    if (e < 8) { h0[e] = (short)hb; l0[e] = (short)lb; }
                    else       { h1[e - 8] = (short)hb; l1[e - 8] = (short)lb; }
                }
            }
            unsigned short* dh = &As_h[sn * LDK + skq * 16];
            unsigned short* dl = &As_l[sn * LDK + skq * 16];
            *(short8*)(dh) = h0; *(short8*)(dh + 8) = h1;
            *(short8*)(dl) = l0; *(short8*)(dl + 8) = l1;
        }
        {
            const int vcol = v0 + sn;
            const bool ok = vcol < VV;
            const float* bsrc = Wfc + (size_t)(k0 + skq * 16) * VV + vcol;
            short8 h0, h1, l0, l1;
            #pragma unroll
            for (int i = 0; i < 16; ++i) {
                const float x = ok ? bsrc[(size_t)i * VV] : 0.f;
                unsigned short hb, lb;
                split_bf16(x, hb, lb);
                if (i < 8) { h0[i] = (short)hb; l0[i] = (short)lb; }
                else       { h1[i - 8] = (short)hb; l1[i - 8] = (short)lb; }
            }
            unsigned short* dh = &Bs_h[sn * LDK + skq * 16];
            unsigned short* dl = &Bs_l[sn * LDK + skq * 16];
            *(short8*)(dh) = h0; *(short8*)(dh + 8) = h1;
            *(short8*)(dl) = l0; *(short8*)(dl + 8) = l1;
        }
        __syncthreads();

        short8 ah[4], al[4], bh[4], bl[4];
        #pragma unroll
        for (int mi = 0; mi < 4; ++mi) {
            const int off = (wm * 64 + mi * 16 + row16) * LDK + quad * 8;
            ah[mi] = *(const short8*)&As_h[off];
            al[mi] = *(const short8*)&As_l[off];
        }
        #pragma unroll
        for (int ni = 0; ni < 4; ++ni) {
            const int off = (wn * 64 + ni * 16 + row16) * LDK + quad * 8;
            bh[ni] = *(const short8*)&Bs_h[off];
            bl[ni] = *(const short8*)&Bs_l[off];
        }
        #pragma unroll
        for (int mi = 0; mi < 4; ++mi) {
            #pragma unroll
            for (int ni = 0; ni < 4; ++ni) {
                acc[mi][ni] = __builtin_amdgcn_mfma_f32_16x16x32_bf16(
                    ah[mi], bh[ni], acc[mi][ni], 0, 0, 0);
                acc[mi][ni] = __builtin_amdgcn_mfma_f32_16x16x32_bf16(
                    ah[mi], bl[ni], acc[mi][ni], 0, 0, 0);
                acc[mi][ni] = __builtin_amdgcn_mfma_f32_16x16x32_bf16(
                    al[mi], bh[ni], acc[mi][ni], 0, 0, 0);
            }
        }
        __syncthreads();
    }

    #pragma unroll
    for (int ni = 0; ni < 4; ++ni) {
        const int v = v0 + wn * 64 + ni * 16 + row16;
        if (v >= VV) continue;
        const float bias = bfc[v];
        #pragma unroll
        for (int mi = 0; mi < 4; ++mi) {
            const int mbase = m0 + wm * 64 + mi * 16 + quad * 4;
            #pragma unroll
            for (int r = 0; r < 4; ++r) {
                const int m = mbase + r;
                const int t_idx = m >> 5;
                const int b_idx = m & 31;
                out[((size_t)b_idx * TT + t_idx) * VV + v] = acc[mi][ni][r] + bias;
            }
        }
    }
}

// ---------------------------------------------------------------------------
extern "C" void kernel_launch(void* const* d_in, const int* in_sizes, int n_in,
                              void* d_out, int out_size, void* d_ws, size_t ws_size,
                              hipStream_t stream) {
    const float* enc      = (const float*)d_in[0];
    const int*   captions = (const int*)  d_in[1];
    const float* Wea      = (const float*)d_in[2];
    const float* bea      = (const float*)d_in[3];
    const float* Wda      = (const float*)d_in[4];
    const float* bda      = (const float*)d_in[5];
    const float* Wfull    = (const float*)d_in[6];
    const float* bfull    = (const float*)d_in[7];
    const float* emb      = (const float*)d_in[8];
    const float* Wih      = (const float*)d_in[9];
    const float* bih      = (const float*)d_in[10];
    const float* Whh      = (const float*)d_in[11];
    const float* bhh      = (const float*)d_in[12];
    const float* Wfc      = (const float*)d_in[13];
    const float* bfc      = (const float*)d_in[14];
    float* out = (float*)d_out;

    float* ws   = (float*)d_ws;
    float* att1 = ws;                          // 1,605,632 f
    float* Hall = att1 + 1605632;              //   327,680 f
    float* Epre = Hall + 327680;               // 1,310,720 f
    float* hbuf = Epre + 1310720;              //    32,768 f (2x double-buffered h)
    float* ctxb = hbuf + 32768;                //     8,192 f
    unsigned* flags = (unsigned*)(ctxb + 8192);//     9,216 u (288 x 32-uint slots)
    float* Wpk  = ctxb + 8192 + NFLAGS;        // 1,572,864 f (packed gate weights)
    float* tail = Wpk + 1572864;               // bf16 tables start here
    unsigned short* Ah   = (unsigned short*)tail;              // 640*512
    unsigned short* Al   = Ah + 640 * 512;
    unsigned short* Wt_h = Al + 640 * 512;                     // VPAD*512
    unsigned short* Wt_l = Wt_h + (size_t)VPAD * HH;
    const size_t need_bytes =
        (size_t)(4867072) * 4 +                       // fp32 scratch (+flags+Wpk)
        (size_t)(2 * 640 * 512) * 2 +                 // Ah/Al
        (size_t)(2 * (size_t)VPAD * HH) * 2;          // Wt_h/Wt_l
    const bool pre = ws_size >= need_bytes;

    att1_kernel<<<dim3(784), dim3(256), 0, stream>>>(enc, Wea, bea, att1, flags);
    epre_kernel<<<dim3(8, 80), dim3(256), 0, stream>>>(captions, emb, Wih, bih, bhh, Epre);
    pack_w_kernel<<<dim3(32), dim3(256), 0, stream>>>(Wih, Whh, Wpk);
    if (pre) {
        split_wfc_kernel<<<dim3(8, VPAD / 64), dim3(256), 0, stream>>>(Wfc, Wt_h, Wt_l);
    }

    int write_split = pre ? 1 : 0;
    void* cargs[] = {
        (void*)&att1, (void*)&enc, (void*)&Wda, (void*)&bda, (void*)&Wfull, (void*)&bfull,
        (void*)&Wpk, (void*)&Epre, (void*)&hbuf, (void*)&ctxb, (void*)&Hall,
        (void*)&Ah, (void*)&Al, (void*)&flags, (void*)&write_split };
    hipError_t cerr = hipLaunchCooperativeKernel(fused_loop_kernel,
                                                 dim3(NBLK), dim3(1024),
                                                 cargs, 0, stream);
    if (cerr != hipSuccess) {
        // Fallback: old per-step loop. Scratch aliased over the Ah/Al table
        // region (written only after the loop completes).
        float* cbuf    = (float*)tail;        // 16,384 f
        float* context = cbuf + 16384;        //  8,192 f
        float* gates   = context + 8192;      // 65,536 f
        for (int t = 0; t < TT; ++t) {
            attn_step_kernel<<<dim3(BB), dim3(1024), 0, stream>>>(
                t, att1, enc, Hall, cbuf, gates, context, Wda, bda, Wfull, bfull);
            gates_kernel<<<dim3(32, 8), dim3(1024), 0, stream>>>(
                t, context, Hall, Epre, Wih, Whh, gates);
        }
        final_update_kernel<<<dim3(64), dim3(256), 0, stream>>>(gates, cbuf, Hall);
        if (pre) {
            split_hall_kernel<<<dim3(1280), dim3(256), 0, stream>>>(Hall, Ah, Al);
        }
    }

    if (pre) {
        gemm_out_mfma_pre<<<dim3(5, 235), dim3(256), 0, stream>>>(
            Ah, Al, Wt_h, Wt_l, bfc, out);
    } else {
        gemm_out_mfma_fb<<<dim3(5, 235), dim3(256), 0, stream>>>(Hall, Wfc, bfc, out);
    }
}

// Round 9
// 993.169 us; speedup vs baseline: 1.1417x; 1.1417x over previous
//
#include <hip/hip_runtime.h>
#include <cstddef>

// Problem constants
#define BB 32
#define PP 196
#define DENC 256
#define EE 512
#define HH 512
#define AA 256
#define VV 30000
#define TT 20
#define BH (BB*HH)          // 16384
#define G4 (4*HH)           // 2048
#define VPAD 30080          // VV padded to multiple of 64
#define NBLK 256            // persistent-kernel grid (one block per CU)
#define NFLAGS 9216         // (32 cflag + 256 gflag) slots x 32 uints (128B pad)

typedef __attribute__((ext_vector_type(8))) short short8;
typedef __attribute__((ext_vector_type(4))) float f32x4;

__device__ __forceinline__ float fast_sigmoid(float x) {
    return 1.f / (1.f + __expf(-x));
}
__device__ __forceinline__ float fast_tanh(float x) {
    x = fminf(fmaxf(x, -15.f), 15.f);
    float e = __expf(2.f * x);
    return (e - 1.f) / (e + 1.f);
}
// truncation split: hi = bf16_trunc(x), lo = bf16_trunc(x - hi)
__device__ __forceinline__ void split_bf16(float x, unsigned short& hi, unsigned short& lo) {
    const unsigned u = __float_as_uint(x);
    hi = (unsigned short)(u >> 16);
    const float r = x - __uint_as_float(u & 0xffff0000u);
    lo = (unsigned short)(__float_as_uint(r) >> 16);
}

// Agent-scope coherent load/store (bypass the non-coherent per-XCD L2; hit the
// coherent point). Used ONLY for the small cross-block payload (ctxb, hbuf).
// Write-through stores mean the flag publish needs NO release semantics ->
// no buffer_wbl2 (L2 writeback scan) anywhere in the persistent loop.
__device__ __forceinline__ float aload(const float* p) {
    const unsigned u = __hip_atomic_load((const unsigned*)p, __ATOMIC_RELAXED,
                                         __HIP_MEMORY_SCOPE_AGENT);
    return __uint_as_float(u);
}
__device__ __forceinline__ void astore(float* p, float v) {
    __hip_atomic_store((unsigned*)p, __float_as_uint(v), __ATOMIC_RELAXED,
                       __HIP_MEMORY_SCOPE_AGENT);
}

// Relaxed spin on a per-producer flag slot (distinct cacheline per producer).
__device__ __forceinline__ void wait_flag(const unsigned* f, unsigned target) {
    while (__hip_atomic_load(f, __ATOMIC_RELAXED, __HIP_MEMORY_SCOPE_AGENT) < target) {
        __builtin_amdgcn_s_sleep(2);
    }
}

// ---------------------------------------------------------------------------
// att1[b,p,a] = enc[b,p,:] @ W_enc_att[:,a] + b_enc_att[a]
// (block 0 also zeroes the flag slots for the fused kernel — per-launch reset)
// ---------------------------------------------------------------------------
__global__ void att1_kernel(const float* __restrict__ enc,
                            const float* __restrict__ W,
                            const float* __restrict__ bias,
                            float* __restrict__ att1,
                            unsigned* __restrict__ flags) {
    const int tid = threadIdx.x;
    if (blockIdx.x == 0) {
        for (int i = tid; i < NFLAGS; i += 256)
            __hip_atomic_store(flags + i, 0u, __ATOMIC_RELAXED, __HIP_MEMORY_SCOPE_AGENT);
    }
    __shared__ float xs[8][DENC];
    const int r0 = blockIdx.x * 8;
    #pragma unroll
    for (int bi = 0; bi < 8; ++bi)
        xs[bi][tid] = enc[(size_t)(r0 + bi) * DENC + tid];
    __syncthreads();
    float acc[8];
    const float bv = bias[tid];
    #pragma unroll
    for (int bi = 0; bi < 8; ++bi) acc[bi] = bv;
    #pragma unroll 8
    for (int k = 0; k < DENC; ++k) {
        const float w = W[k * AA + tid];
        #pragma unroll
        for (int bi = 0; bi < 8; ++bi) acc[bi] += xs[bi][k] * w;
    }
    #pragma unroll
    for (int bi = 0; bi < 8; ++bi)
        att1[(size_t)(r0 + bi) * AA + tid] = acc[bi];
}

// ---------------------------------------------------------------------------
// Epre[m, j] = emb[captions[b,t]] @ W_ih[0:512, j] + b_ih[j] + b_hh[j]
// ---------------------------------------------------------------------------
__global__ void epre_kernel(const int* __restrict__ captions,
                            const float* __restrict__ emb,
                            const float* __restrict__ Wih,
                            const float* __restrict__ bih,
                            const float* __restrict__ bhh,
                            float* __restrict__ Epre) {
    __shared__ float xs[8][EE];
    const int tid = threadIdx.x;
    const int jc = blockIdx.x;     // 0..7
    const int mg = blockIdx.y;     // 0..79
    const int j = jc * 256 + tid;

    #pragma unroll
    for (int i = 0; i < 8; ++i) {
        const int m = mg * 8 + i;
        const int t = m >> 5, b = m & 31;
        const int cap = captions[b * TT + t];
        const float* erow = emb + (size_t)cap * EE;
        xs[i][tid]       = erow[tid];
        xs[i][tid + 256] = erow[tid + 256];
    }
    __syncthreads();

    float acc[8];
    const float bv = bih[j] + bhh[j];
    #pragma unroll
    for (int i = 0; i < 8; ++i) acc[i] = bv;
    #pragma unroll 8
    for (int k = 0; k < EE; ++k) {
        const float w = Wih[(size_t)k * G4 + j];
        #pragma unroll
        for (int i = 0; i < 8; ++i) acc[i] += xs[i][k] * w;
    }
    #pragma unroll
    for (int i = 0; i < 8; ++i)
        Epre[(size_t)(mg * 8 + i) * G4 + j] = acc[i];
}

// ---------------------------------------------------------------------------
// One-time weight repack for the fused gates GEMM.
// Wpk[jc][k][cl] = (k < 256) ? Wih[512+k][col] : Whh[k-256][col]
//   where col = (cl>>4)*512 + jc*16 + (cl&15),  jc=0..31, k=0..767, cl=0..63.
// ---------------------------------------------------------------------------
__global__ void pack_w_kernel(const float* __restrict__ Wih,
                              const float* __restrict__ Whh,
                              float* __restrict__ Wpk) {
    const int jc = blockIdx.x;     // 0..31
    const int tid = threadIdx.x;   // 0..255
    float* dst = Wpk + (size_t)jc * 768 * 64;
    for (int i = tid; i < 768 * 64; i += 256) {
        const int k = i >> 6, cl = i & 63;
        const int col = ((cl >> 4) * 512) + jc * 16 + (cl & 15);
        const float v = (k < 256) ? Wih[(size_t)(512 + k) * G4 + col]
                                  : Whh[(size_t)(k - 256) * G4 + col];
        dst[i] = v;
    }
}

// ---------------------------------------------------------------------------
// FUSED persistent time-loop kernel: 256 blocks x 1024 threads, cooperative.
// Sync via per-block flags; ALL cross-block payload traffic (ctxb, hbuf) is
// agent-coherent (write-through astore / L2-bypassing aload), so flag stores
// are RELAXED: no buffer_wbl2, no cache invalidates in the loop.
//   cflag[b]   (b=0..31) : attention block b publishes ctxb(t)  -> value t+1
//   gflag[bid] (0..255)  : gates block publishes its h(t) slice -> value t+1
// __syncthreads() before each flag store drains vmcnt in every wave, so
// payload stores are globally performed before the flag becomes visible.
// ---------------------------------------------------------------------------
__global__ __launch_bounds__(1024) void fused_loop_kernel(
        const float* __restrict__ att1,
        const float* __restrict__ enc,
        const float* __restrict__ Wda,
        const float* __restrict__ bda,
        const float* __restrict__ Wfull,
        const float* __restrict__ bfull,
        const float* __restrict__ Wpk,
        const float* __restrict__ Epre,
        float* __restrict__ hbuf,        // [2][32][512]
        float* __restrict__ ctxb,        // [32][256]
        float* __restrict__ Hall,        // [640][512]
        unsigned short* __restrict__ Ah,
        unsigned short* __restrict__ Al,
        unsigned* flags,
        int write_split) {
    const int bid = blockIdx.x;        // 0..255
    const int tid = threadIdx.x;       // 0..1023
    const int jc = bid & 31;           // h-dim slice
    const int bg = bid >> 5;           // 0..7 (4 batches each)

    unsigned* cflag = flags;           // [32] slots, stride 32 uints (128B)
    unsigned* gflag = flags + 32 * 32; // [256] slots, stride 32 uints

    __shared__ float h_s[HH];
    __shared__ float part[4][256];
    __shared__ float att2_s[AA];
    __shared__ float e_s[256];
    __shared__ float red_s[256];
    __shared__ float xs[4][768];
    __shared__ float gred[256];

    float c_reg = 0.f;                 // per-thread c state (threads tid<64 use it)

    for (int t = 0; t < TT; ++t) {
        float* hprev = hbuf + ((t + 1) & 1) * 16384;   // h(t-1)

        // ---------------- attention phase (blocks 0..31) ----------------
        if (bid < 32) {
            const int b = bid;
            if (t > 0) {
                // wait for h(t-1)[b] = all 32 gates blocks of group b>>2
                if (tid < 32) wait_flag(gflag + ((b >> 2) * 32 + tid) * 32, (unsigned)t);
                asm volatile("" ::: "memory");
                __syncthreads();
            }
            if (tid < 512) h_s[tid] = (t == 0) ? 0.f : aload(&hprev[b * HH + tid]);
            __syncthreads();
            // att2 = h @ Wda + bda (4-way split-K)
            {
                const int q = tid >> 8, col = tid & 255;
                const float* W = Wda + (size_t)(q * 128) * AA + col;
                const float* hh = h_s + q * 128;
                float acc = 0.f;
                #pragma unroll 16
                for (int k = 0; k < 128; ++k) acc += hh[k] * W[(size_t)k * AA];
                part[q][col] = acc;
            }
            __syncthreads();
            if (tid < 256)
                att2_s[tid] = part[0][tid] + part[1][tid] + part[2][tid] + part[3][tid] + bda[tid];
            __syncthreads();
            // e[p], one wave per p
            {
                const int wave = tid >> 6, lane = tid & 63;
                const float bf0 = bfull[0];
                for (int p = wave; p < PP; p += 16) {
                    const float* row = att1 + ((size_t)b * PP + p) * AA;
                    float s = 0.f;
                    #pragma unroll
                    for (int q = 0; q < 4; ++q) {
                        const int a = lane + q * 64;
                        s += fast_tanh(row[a] + att2_s[a]) * Wfull[a];
                    }
                    #pragma unroll
                    for (int off = 32; off > 0; off >>= 1) s += __shfl_down(s, off, 64);
                    if (lane == 0) e_s[p] = s + bf0;
                }
            }
            __syncthreads();
            // softmax over p
            const float val = (tid < PP) ? e_s[tid] : -3.4e38f;
            if (tid < 256) red_s[tid] = val;
            __syncthreads();
            #pragma unroll
            for (int s = 128; s > 0; s >>= 1) {
                if (tid < s) red_s[tid] = fmaxf(red_s[tid], red_s[tid + s]);
                __syncthreads();
            }
            const float mx = red_s[0];
            __syncthreads();
            const float ex = (tid < PP) ? __expf(val - mx) : 0.f;
            if (tid < 256) red_s[tid] = ex;
            __syncthreads();
            #pragma unroll
            for (int s = 128; s > 0; s >>= 1) {
                if (tid < s) red_s[tid] += red_s[tid + s];
                __syncthreads();
            }
            const float inv = 1.f / red_s[0];
            __syncthreads();
            if (tid < 256) e_s[tid] = ex * inv;   // alpha
            __syncthreads();
            // context = alpha @ enc
            {
                const int q = tid >> 8, col = tid & 255;
                const float* erow = enc + (size_t)b * PP * DENC + col;
                float acc = 0.f;
                const int p0 = q * 49;
                #pragma unroll 7
                for (int p = p0; p < p0 + 49; ++p) acc += e_s[p] * erow[(size_t)p * DENC];
                part[q][col] = acc;
            }
            __syncthreads();
            if (tid < 256)
                astore(&ctxb[b * DENC + tid],
                       part[0][tid] + part[1][tid] + part[2][tid] + part[3][tid]);
            __syncthreads();   // drains vmcnt in all waves -> payload performed
            if (tid == 0)
                __hip_atomic_store(cflag + b * 32, (unsigned)(t + 1),
                                   __ATOMIC_RELAXED, __HIP_MEMORY_SCOPE_AGENT);
        }

        // ---------------- gates + pointwise phase (all blocks) ----------------
        // wait for ctxb of this block's 4 batches
        if (tid < 4) wait_flag(cflag + (bg * 4 + tid) * 32, (unsigned)(t + 1));
        asm volatile("" ::: "memory");
        __syncthreads();

        // stage x = [context(256), h(512)] for 4 batches (coherent loads)
        #pragma unroll
        for (int ii = 0; ii < 3; ++ii) {
            const int idx = tid + ii * 1024;
            const int bi = idx / 768;
            const int k = idx - bi * 768;
            const int b = bg * 4 + bi;
            xs[bi][k] = (k < 256) ? aload(&ctxb[b * DENC + k])
                                  : ((t > 0) ? aload(&hprev[b * HH + (k - 256)]) : 0.f);
        }
        __syncthreads();
        {
            const int kq = tid >> 8;            // 0..3, wave-uniform
            const int r = tid & 255;
            const int bl = r >> 6;              // local batch 0..3
            const int cl = r & 63;              // g*16 + hdl
            const float* xr = xs[bl] + kq * 192;
            const float* Wp = Wpk + ((size_t)jc * 768 + kq * 192) * 64 + cl;
            float acc = 0.f;
            #pragma unroll 16
            for (int k = 0; k < 192; ++k) acc += xr[k] * Wp[(size_t)k * 64];
            part[kq][r] = acc;
        }
        __syncthreads();
        if (tid < 256) {
            const int bl = tid >> 6;
            const int cl = tid & 63;
            const int b = bg * 4 + bl;
            const int col = ((cl >> 4) * 512) + jc * 16 + (cl & 15);
            gred[tid] = part[0][tid] + part[1][tid] + part[2][tid] + part[3][tid]
                      + Epre[(size_t)(t * BB + b) * G4 + col];
        }
        __syncthreads();
        if (tid < 64) {
            const int bl = tid >> 4;            // 0..3
            const int hdl = tid & 15;
            const float gi = gred[bl * 64 +  0 + hdl];
            const float gf = gred[bl * 64 + 16 + hdl];
            const float gg = gred[bl * 64 + 32 + hdl];
            const float go = gred[bl * 64 + 48 + hdl];
            const float cn = fast_sigmoid(gf) * c_reg + fast_sigmoid(gi) * fast_tanh(gg);
            const float hn = fast_sigmoid(go) * fast_tanh(cn);
            c_reg = cn;
            const int b = bg * 4 + bl;
            const int hd = jc * 16 + hdl;
            astore(&hbuf[(t & 1) * 16384 + b * HH + hd], hn);   // coherent publish
            const size_t mi = (size_t)(t * BB + b) * HH + hd;
            Hall[mi] = hn;
            if (write_split) {
                unsigned short hh_, ll_;
                split_bf16(hn, hh_, ll_);
                Ah[mi] = hh_;
                Al[mi] = ll_;
            }
        }
        if (t < TT - 1) {
            __syncthreads();   // drains vmcnt -> h publish performed
            if (tid == 0)
                __hip_atomic_store(gflag + bid * 32, (unsigned)(t + 1),
                                   __ATOMIC_RELAXED, __HIP_MEMORY_SCOPE_AGENT);
        }
    }
}

// ---------------------------------------------------------------------------
// FALLBACK per-timestep kernels (used only if cooperative launch fails)
// ---------------------------------------------------------------------------
__global__ __launch_bounds__(1024) void attn_step_kernel(
        int t,
        const float* __restrict__ att1,
        const float* __restrict__ enc,
        float* __restrict__ Hall,
        float* __restrict__ cbuf,
        const float* __restrict__ gates,
        float* __restrict__ context,
        const float* __restrict__ Wda,
        const float* __restrict__ bda,
        const float* __restrict__ Wfull,
        const float* __restrict__ bfull) {
    __shared__ float h_s[HH];
    __shared__ float part[4][256];
    __shared__ float att2_s[AA];
    __shared__ float e_s[256];
    __shared__ float red_s[256];
    const int b = blockIdx.x;
    const int tid = threadIdx.x;

    if (tid < 512) {
        if (t == 0) {
            h_s[tid] = 0.f;
            cbuf[b * HH + tid] = 0.f;
        } else {
            const float* g = gates + b * G4;
            const float gi = g[tid];
            const float gf = g[HH + tid];
            const float gg = g[2 * HH + tid];
            const float go = g[3 * HH + tid];
            const float cp = cbuf[b * HH + tid];
            const float cn = fast_sigmoid(gf) * cp + fast_sigmoid(gi) * fast_tanh(gg);
            const float hn = fast_sigmoid(go) * fast_tanh(cn);
            cbuf[b * HH + tid] = cn;
            Hall[(size_t)(t - 1) * BH + b * HH + tid] = hn;
            h_s[tid] = hn;
        }
    }
    __syncthreads();

    {
        const int q = tid >> 8, col = tid & 255;
        const float* W = Wda + (size_t)(q * 128) * AA + col;
        const float* hh = h_s + q * 128;
        float acc = 0.f;
        #pragma unroll 16
        for (int k = 0; k < 128; ++k) acc += hh[k] * W[(size_t)k * AA];
        part[q][col] = acc;
    }
    __syncthreads();
    if (tid < 256)
        att2_s[tid] = part[0][tid] + part[1][tid] + part[2][tid] + part[3][tid] + bda[tid];
    __syncthreads();

    {
        const int wave = tid >> 6, lane = tid & 63;
        const float bf0 = bfull[0];
        for (int p = wave; p < PP; p += 16) {
            const float* row = att1 + ((size_t)b * PP + p) * AA;
            float s = 0.f;
            #pragma unroll
            for (int q = 0; q < 4; ++q) {
                const int a = lane + q * 64;
                s += fast_tanh(row[a] + att2_s[a]) * Wfull[a];
            }
            #pragma unroll
            for (int off = 32; off > 0; off >>= 1) s += __shfl_down(s, off, 64);
            if (lane == 0) e_s[p] = s + bf0;
        }
    }
    __syncthreads();

    const float val = (tid < PP) ? e_s[tid] : -3.4e38f;
    if (tid < 256) red_s[tid] = val;
    __syncthreads();
    #pragma unroll
    for (int s = 128; s > 0; s >>= 1) {
        if (tid < s) red_s[tid] = fmaxf(red_s[tid], red_s[tid + s]);
        __syncthreads();
    }
    const float mx = red_s[0];
    __syncthreads();
    const float ex = (tid < PP) ? __expf(val - mx) : 0.f;
    if (tid < 256) red_s[tid] = ex;
    __syncthreads();
    #pragma unroll
    for (int s = 128; s > 0; s >>= 1) {
        if (tid < s) red_s[tid] += red_s[tid + s];
        __syncthreads();
    }
    const float inv = 1.f / red_s[0];
    __syncthreads();
    if (tid < 256) e_s[tid] = ex * inv;
    __syncthreads();

    {
        const int q = tid >> 8, col = tid & 255;
        const float* erow = enc + (size_t)b * PP * DENC + col;
        float acc = 0.f;
        const int p0 = q * 49;
        #pragma unroll 7
        for (int p = p0; p < p0 + 49; ++p) acc += e_s[p] * erow[(size_t)p * DENC];
        part[q][col] = acc;
    }
    __syncthreads();
    if (tid < 256)
        context[b * DENC + tid] = part[0][tid] + part[1][tid] + part[2][tid] + part[3][tid];
}

__global__ __launch_bounds__(1024) void gates_kernel(
        int t,
        const float* __restrict__ context,
        const float* __restrict__ Hall,
        const float* __restrict__ Epre,
        const float* __restrict__ Wih,
        const float* __restrict__ Whh,
        float* __restrict__ gates) {
    __shared__ float xs[4][768];
    __shared__ float part[4][256];
    const int tid = threadIdx.x;
    const int jc = blockIdx.x;
    const int bg = blockIdx.y;

    for (int idx = tid; idx < 4 * 768; idx += 1024) {
        const int bi = idx / 768;
        const int k = idx - bi * 768;
        const int b = bg * 4 + bi;
        float v;
        if (k < 256) v = context[b * DENC + k];
        else v = (t > 0) ? Hall[(size_t)(t - 1) * BH + b * HH + (k - 256)] : 0.f;
        xs[bi][k] = v;
    }
    __syncthreads();

    const int kq = tid >> 8;
    const int r = tid & 255;
    const int jl = r & 63, bl = r >> 6;
    const int j = jc * 64 + jl;
    const float* xrow = xs[bl];

    float acc = 0.f;
    if (kq == 0) {
        const float* W1 = Wih + (size_t)512 * G4 + j;
        #pragma unroll 16
        for (int k = 0; k < 192; ++k) acc += xrow[k] * W1[(size_t)k * G4];
    } else if (kq == 1) {
        const float* W1 = Wih + (size_t)704 * G4 + j;
        #pragma unroll 16
        for (int k = 0; k < 64; ++k) acc += xrow[192 + k] * W1[(size_t)k * G4];
        const float* W2 = Whh + j;
        #pragma unroll 16
        for (int k = 0; k < 128; ++k) acc += xrow[256 + k] * W2[(size_t)k * G4];
    } else if (kq == 2) {
        const float* W2 = Whh + (size_t)128 * G4 + j;
        #pragma unroll 16
        for (int k = 0; k < 192; ++k) acc += xrow[384 + k] * W2[(size_t)k * G4];
    } else {
        const float* W2 = Whh + (size_t)320 * G4 + j;
        #pragma unroll 16
        for (int k = 0; k < 192; ++k) acc += xrow[576 + k] * W2[(size_t)k * G4];
    }
    part[kq][r] = acc;
    __syncthreads();

    if (tid < 256) {
        const int b = bg * 4 + bl;
        gates[(size_t)b * G4 + j] = part[0][tid] + part[1][tid] + part[2][tid] + part[3][tid]
                                  + Epre[(size_t)(t * BB + b) * G4 + j];
    }
}

__global__ void final_update_kernel(const float* __restrict__ gates,
                                    const float* __restrict__ cbuf,
                                    float* __restrict__ Hall) {
    const int idx = blockIdx.x * 256 + threadIdx.x;
    const int b = idx >> 9, hi = idx & 511;
    const float* g = gates + b * G4;
    const float gi = g[hi];
    const float gf = g[HH + hi];
    const float gg = g[2 * HH + hi];
    const float go = g[3 * HH + hi];
    const float cp = cbuf[idx];
    const float cn = fast_sigmoid(gf) * cp + fast_sigmoid(gi) * fast_tanh(gg);
    const float hn = fast_sigmoid(go) * fast_tanh(cn);
    Hall[(size_t)(TT - 1) * BH + idx] = hn;
}

__global__ void split_hall_kernel(const float* __restrict__ Hall,
                                  unsigned short* __restrict__ Ah,
                                  unsigned short* __restrict__ Al) {
    const int idx = blockIdx.x * 256 + threadIdx.x;
    unsigned short h, l;
    split_bf16(Hall[idx], h, l);
    Ah[idx] = h; Al[idx] = l;
}

// ---------------------------------------------------------------------------
// Transpose + split Wfc[k][v] -> Wt_h/Wt_l[v][k], v padded to VPAD (zero-fill).
// ---------------------------------------------------------------------------
__global__ void split_wfc_kernel(const float* __restrict__ Wfc,
                                 unsigned short* __restrict__ Wt_h,
                                 unsigned short* __restrict__ Wt_l) {
    __shared__ unsigned short th[64][66];
    __shared__ unsigned short tl[64][66];
    const int tid = threadIdx.x;
    const int k0 = blockIdx.x * 64;
    const int v0 = blockIdx.y * 64;

    const int c = tid & 63, r0 = tid >> 6;
    #pragma unroll
    for (int i = 0; i < 16; ++i) {
        const int r = r0 + i * 4;
        const int v = v0 + c;
        const float x = (v < VV) ? Wfc[(size_t)(k0 + r) * VV + v] : 0.f;
        unsigned short h, l;
        split_bf16(x, h, l);
        th[r][c] = h; tl[r][c] = l;
    }
    __syncthreads();

    const int v = tid >> 2, q = tid & 3;
    short8 oh0, oh1, ol0, ol1;
    #pragma unroll
    for (int i = 0; i < 8; ++i) {
        oh0[i] = (short)th[q * 16 + i][v];
        oh1[i] = (short)th[q * 16 + 8 + i][v];
        ol0[i] = (short)tl[q * 16 + i][v];
        ol1[i] = (short)tl[q * 16 + 8 + i][v];
    }
    unsigned short* dh = Wt_h + (size_t)(v0 + v) * HH + k0 + q * 16;
    unsigned short* dl = Wt_l + (size_t)(v0 + v) * HH + k0 + q * 16;
    *(short8*)(dh) = oh0; *(short8*)(dh + 8) = oh1;
    *(short8*)(dl) = ol0; *(short8*)(dl + 8) = ol1;
}

// ---------------------------------------------------------------------------
// Output projection, pre-split path: pure-copy staging, bf16x3 MFMA.
// ---------------------------------------------------------------------------
#define LDK 40   // padded LDS row length in bf16 units

__global__ __launch_bounds__(256) void gemm_out_mfma_pre(
        const unsigned short* __restrict__ Ah,
        const unsigned short* __restrict__ Al,
        const unsigned short* __restrict__ Wt_h,
        const unsigned short* __restrict__ Wt_l,
        const float* __restrict__ bfc,
        float* __restrict__ out) {
    __shared__ unsigned short As_h[128 * LDK];
    __shared__ unsigned short As_l[128 * LDK];
    __shared__ unsigned short Bs_h[128 * LDK];
    __shared__ unsigned short Bs_l[128 * LDK];

    const int tid = threadIdx.x;
    const int m0 = blockIdx.x * 128;
    const int v0 = blockIdx.y * 128;

    const int wave = tid >> 6, lane = tid & 63;
    const int wm = wave & 1, wn = wave >> 1;
    const int row16 = lane & 15, quad = lane >> 4;

    const int sn = tid & 127;
    const int skq = tid >> 7;

    f32x4 acc[4][4] = {};

    #pragma unroll 1
    for (int k0 = 0; k0 < HH; k0 += 32) {
        {
            const size_t src = (size_t)(m0 + sn) * HH + k0 + skq * 16;
            const short8 h0 = *(const short8*)(Ah + src);
            const short8 h1 = *(const short8*)(Ah + src + 8);
            const short8 l0 = *(const short8*)(Al + src);
            const short8 l1 = *(const short8*)(Al + src + 8);
            unsigned short* dh = &As_h[sn * LDK + skq * 16];
            unsigned short* dl = &As_l[sn * LDK + skq * 16];
            *(short8*)(dh) = h0; *(short8*)(dh + 8) = h1;
            *(short8*)(dl) = l0; *(short8*)(dl + 8) = l1;
        }
        {
            const size_t src = (size_t)(v0 + sn) * HH + k0 + skq * 16;
            const short8 h0 = *(const short8*)(Wt_h + src);
            const short8 h1 = *(const short8*)(Wt_h + src + 8);
            const short8 l0 = *(const short8*)(Wt_l + src);
            const short8 l1 = *(const short8*)(Wt_l + src + 8);
            unsigned short* dh = &Bs_h[sn * LDK + skq * 16];
            unsigned short* dl = &Bs_l[sn * LDK + skq * 16];
            *(short8*)(dh) = h0; *(short8*)(dh + 8) = h1;
            *(short8*)(dl) = l0; *(short8*)(dl + 8) = l1;
        }
        __syncthreads();

        short8 ah[4], al[4], bh[4], bl[4];
        #pragma unroll
        for (int mi = 0; mi < 4; ++mi) {
            const int off = (wm * 64 + mi * 16 + row16) * LDK + quad * 8;
            ah[mi] = *(const short8*)&As_h[off];
            al[mi] = *(const short8*)&As_l[off];
        }
        #pragma unroll
        for (int ni = 0; ni < 4; ++ni) {
            const int off = (wn * 64 + ni * 16 + row16) * LDK + quad * 8;
            bh[ni] = *(const short8*)&Bs_h[off];
            bl[ni] = *(const short8*)&Bs_l[off];
        }
        #pragma unroll
        for (int mi = 0; mi < 4; ++mi) {
            #pragma unroll
            for (int ni = 0; ni < 4; ++ni) {
                acc[mi][ni] = __builtin_amdgcn_mfma_f32_16x16x32_bf16(
                    ah[mi], bh[ni], acc[mi][ni], 0, 0, 0);
                acc[mi][ni] = __builtin_amdgcn_mfma_f32_16x16x32_bf16(
                    ah[mi], bl[ni], acc[mi][ni], 0, 0, 0);
                acc[mi][ni] = __builtin_amdgcn_mfma_f32_16x16x32_bf16(
                    al[mi], bh[ni], acc[mi][ni], 0, 0, 0);
            }
        }
        __syncthreads();
    }

    #pragma unroll
    for (int ni = 0; ni < 4; ++ni) {
        const int v = v0 + wn * 64 + ni * 16 + row16;
        if (v >= VV) continue;
        const float bias = bfc[v];
        #pragma unroll
        for (int mi = 0; mi < 4; ++mi) {
            const int mbase = m0 + wm * 64 + mi * 16 + quad * 4;
            #pragma unroll
            for (int r = 0; r < 4; ++r) {
                const int m = mbase + r;
                const int t_idx = m >> 5;
                const int b_idx = m & 31;
                out[((size_t)b_idx * TT + t_idx) * VV + v] = acc[mi][ni][r] + bias;
            }
        }
    }
}

// ---------------------------------------------------------------------------
// Fallback gemm (in-kernel split) — used when ws is too small for tables.
// ---------------------------------------------------------------------------
__global__ __launch_bounds__(256) void gemm_out_mfma_fb(
        const float* __restrict__ Hall,
        const float* __restrict__ Wfc,
        const float* __restrict__ bfc,
        float* __restrict__ out) {
    __shared__ unsigned short As_h[128 * LDK];
    __shared__ unsigned short As_l[128 * LDK];
    __shared__ unsigned short Bs_h[128 * LDK];
    __shared__ unsigned short Bs_l[128 * LDK];

    const int tid = threadIdx.x;
    const int m0 = blockIdx.x * 128;
    const int v0 = blockIdx.y * 128;

    const int wave = tid >> 6, lane = tid & 63;
    const int wm = wave & 1, wn = wave >> 1;
    const int row16 = lane & 15, quad = lane >> 4;

    const int sn = tid & 127;
    const int skq = tid >> 7;

    f32x4 acc[4][4] = {};

    #pragma unroll 1
    for (int k0 = 0; k0 < HH; k0 += 32) {
        {
            const float* asrc = Hall + (size_t)(m0 + sn) * HH + k0 + skq * 16;
            short8 h0, h1, l0, l1;
            #pragma unroll
            for (int i = 0; i < 16; i += 4) {
                const float4 v = *reinterpret_cast<const float4*>(asrc + i);
                const float vv[4] = {v.x, v.y, v.z, v.w};
                #pragma unroll
                for (int jj = 0; jj < 4; ++jj) {
                    unsigned short hb, lb;
                    split_bf16(vv[jj], hb, lb);
                    const int e = i + jj;
                    if (e < 8) { h0[e] = (short)hb; l0[e] = (short)lb; }
                    else       { h1[e - 8] = (short)hb; l1[e - 8] = (short)lb; }
                }
            }
            unsigned short* dh = &As_h[sn * LDK + skq * 16];
            unsigned short* dl = &As_l[sn * LDK + skq * 16];
            *(short8*)(dh) = h0; *(short8*)(dh + 8) = h1;
            *(short8*)(dl) = l0; *(short8*)(dl + 8) = l1;
        }
        {
            const int vcol = v0 + sn;
            const bool ok = vcol < VV;
            const float* bsrc = Wfc + (size_t)(k0 + skq * 16) * VV + vcol;
            short8 h0, h1, l0, l1;
            #pragma unroll
            for (int i = 0; i < 16; ++i) {
                const float x = ok ? bsrc[(size_t)i * VV] : 0.f;
                unsigned short hb, lb;
                split_bf16(x, hb, lb);
                if (i < 8) { h0[i] = (short)hb; l0[i] = (short)lb; }
                else       { h1[i - 8] = (short)hb; l1[i - 8] = (short)lb; }
            }
            unsigned short* dh = &Bs_h[sn * LDK + skq * 16];
            unsigned short* dl = &Bs_l[sn * LDK + skq * 16];
            *(short8*)(dh) = h0; *(short8*)(dh + 8) = h1;
            *(short8*)(dl) = l0; *(short8*)(dl + 8) = l1;
        }
        __syncthreads();

        short8 ah[4], al[4], bh[4], bl[4];
        #pragma unroll
        for (int mi = 0; mi < 4; ++mi) {
            const int off = (wm * 64 + mi * 16 + row16) * LDK + quad * 8;
            ah[mi] = *(const short8*)&As_h[off];
            al[mi] = *(const short8*)&As_l[off];
        }
        #pragma unroll
        for (int ni = 0; ni < 4; ++ni) {
            const int off = (wn * 64 + ni * 16 + row16) * LDK + quad * 8;
            bh[ni] = *(const short8*)&Bs_h[off];
            bl[ni] = *(const short8*)&Bs_l[off];
        }
        #pragma unroll
        for (int mi = 0; mi < 4; ++mi) {
            #pragma unroll
            for (int ni = 0; ni < 4; ++ni) {
                acc[mi][ni] = __builtin_amdgcn_mfma_f32_16x16x32_bf16(
                    ah[mi], bh[ni], acc[mi][ni], 0, 0, 0);
                acc[mi][ni] = __builtin_amdgcn_mfma_f32_16x16x32_bf16(
                    ah[mi], bl[ni], acc[mi][ni], 0, 0, 0);
                acc[mi][ni] = __builtin_amdgcn_mfma_f32_16x16x32_bf16(
                    al[mi], bh[ni], acc[mi][ni], 0, 0, 0);
            }
        }
        __syncthreads();
    }

    #pragma unroll
    for (int ni = 0; ni < 4; ++ni) {
        const int v = v0 + wn * 64 + ni * 16 + row16;
        if (v >= VV) continue;
        const float bias = bfc[v];
        #pragma unroll
        for (int mi = 0; mi < 4; ++mi) {
            const int mbase = m0 + wm * 64 + mi * 16 + quad * 4;
            #pragma unroll
            for (int r = 0; r < 4; ++r) {
                const int m = mbase + r;
                const int t_idx = m >> 5;
                const int b_idx = m & 31;
                out[((size_t)b_idx * TT + t_idx) * VV + v] = acc[mi][ni][r] + bias;
            }
        }
    }
}

// ---------------------------------------------------------------------------
extern "C" void kernel_launch(void* const* d_in, const int* in_sizes, int n_in,
                              void* d_out, int out_size, void* d_ws, size_t ws_size,
                              hipStream_t stream) {
    const float* enc      = (const float*)d_in[0];
    const int*   captions = (const int*)  d_in[1];
    const float* Wea      = (const float*)d_in[2];
    const float* bea      = (const float*)d_in[3];
    const float* Wda      = (const float*)d_in[4];
    const float* bda      = (const float*)d_in[5];
    const float* Wfull    = (const float*)d_in[6];
    const float* bfull    = (const float*)d_in[7];
    const float* emb      = (const float*)d_in[8];
    const float* Wih      = (const float*)d_in[9];
    const float* bih      = (const float*)d_in[10];
    const float* Whh      = (const float*)d_in[11];
    const float* bhh      = (const float*)d_in[12];
    const float* Wfc      = (const float*)d_in[13];
    const float* bfc      = (const float*)d_in[14];
    float* out = (float*)d_out;

    float* ws   = (float*)d_ws;
    float* att1 = ws;                          // 1,605,632 f
    float* Hall = att1 + 1605632;              //   327,680 f
    float* Epre = Hall + 327680;               // 1,310,720 f
    float* hbuf = Epre + 1310720;              //    32,768 f (2x double-buffered h)
    float* ctxb = hbuf + 32768;                //     8,192 f
    unsigned* flags = (unsigned*)(ctxb + 8192);//     9,216 u (288 x 32-uint slots)
    float* Wpk  = ctxb + 8192 + NFLAGS;        // 1,572,864 f (packed gate weights)
    float* tail = Wpk + 1572864;               // bf16 tables start here
    unsigned short* Ah   = (unsigned short*)tail;              // 640*512
    unsigned short* Al   = Ah + 640 * 512;
    unsigned short* Wt_h = Al + 640 * 512;                     // VPAD*512
    unsigned short* Wt_l = Wt_h + (size_t)VPAD * HH;
    const size_t need_bytes =
        (size_t)(4867072) * 4 +                       // fp32 scratch (+flags+Wpk)
        (size_t)(2 * 640 * 512) * 2 +                 // Ah/Al
        (size_t)(2 * (size_t)VPAD * HH) * 2;          // Wt_h/Wt_l
    const bool pre = ws_size >= need_bytes;

    att1_kernel<<<dim3(784), dim3(256), 0, stream>>>(enc, Wea, bea, att1, flags);
    epre_kernel<<<dim3(8, 80), dim3(256), 0, stream>>>(captions, emb, Wih, bih, bhh, Epre);
    pack_w_kernel<<<dim3(32), dim3(256), 0, stream>>>(Wih, Whh, Wpk);
    if (pre) {
        split_wfc_kernel<<<dim3(8, VPAD / 64), dim3(256), 0, stream>>>(Wfc, Wt_h, Wt_l);
    }

    int write_split = pre ? 1 : 0;
    void* cargs[] = {
        (void*)&att1, (void*)&enc, (void*)&Wda, (void*)&bda, (void*)&Wfull, (void*)&bfull,
        (void*)&Wpk, (void*)&Epre, (void*)&hbuf, (void*)&ctxb, (void*)&Hall,
        (void*)&Ah, (void*)&Al, (void*)&flags, (void*)&write_split };
    hipError_t cerr = hipLaunchCooperativeKernel(fused_loop_kernel,
                                                 dim3(NBLK), dim3(1024),
                                                 cargs, 0, stream);
    if (cerr != hipSuccess) {
        // Fallback: old per-step loop. Scratch aliased over the Ah/Al table
        // region (written only after the loop completes).
        float* cbuf    = (float*)tail;        // 16,384 f
        float* context = cbuf + 16384;        //  8,192 f
        float* gates   = context + 8192;      // 65,536 f
        for (int t = 0; t < TT; ++t) {
            attn_step_kernel<<<dim3(BB), dim3(1024), 0, stream>>>(
                t, att1, enc, Hall, cbuf, gates, context, Wda, bda, Wfull, bfull);
            gates_kernel<<<dim3(32, 8), dim3(1024), 0, stream>>>(
                t, context, Hall, Epre, Wih, Whh, gates);
        }
        final_update_kernel<<<dim3(64), dim3(256), 0, stream>>>(gates, cbuf, Hall);
        if (pre) {
            split_hall_kernel<<<dim3(1280), dim3(256), 0, stream>>>(Hall, Ah, Al);
        }
    }

    if (pre) {
        gemm_out_mfma_pre<<<dim3(5, 235), dim3(256), 0, stream>>>(
            Ah, Al, Wt_h, Wt_l, bfc, out);
    } else {
        gemm_out_mfma_fb<<<dim3(5, 235), dim3(256), 0, stream>>>(Hall, Wfc, bfc, out);
    }
}

// Round 10
// 963.789 us; speedup vs baseline: 1.1765x; 1.0305x over previous
//
#include <hip/hip_runtime.h>
#include <cstddef>

// Problem constants
#define BB 32
#define PP 196
#define DENC 256
#define EE 512
#define HH 512
#define AA 256
#define VV 30000
#define TT 20
#define BH (BB*HH)          // 16384
#define G4 (4*HH)           // 2048
#define VPAD 30080          // VV padded to multiple of 64
#define NBLK 256            // persistent-kernel grid (one block per CU)
#define NFLAGS 9216         // (32 cflag + 256 gflag) slots x 32 uints (128B pad)

typedef __attribute__((ext_vector_type(8))) short short8;
typedef __attribute__((ext_vector_type(4))) float f32x4;

__device__ __forceinline__ float fast_sigmoid(float x) {
    return 1.f / (1.f + __expf(-x));
}
__device__ __forceinline__ float fast_tanh(float x) {
    x = fminf(fmaxf(x, -15.f), 15.f);
    float e = __expf(2.f * x);
    return (e - 1.f) / (e + 1.f);
}
// truncation split: hi = bf16_trunc(x), lo = bf16_trunc(x - hi)
__device__ __forceinline__ void split_bf16(float x, unsigned short& hi, unsigned short& lo) {
    const unsigned u = __float_as_uint(x);
    hi = (unsigned short)(u >> 16);
    const float r = x - __uint_as_float(u & 0xffff0000u);
    lo = (unsigned short)(__float_as_uint(r) >> 16);
}

// Agent-scope coherent load/store (bypass the non-coherent per-XCD L2; hit the
// coherent point). Used ONLY for the small cross-block payload (ctxb, hbuf).
__device__ __forceinline__ float aload(const float* p) {
    const unsigned u = __hip_atomic_load((const unsigned*)p, __ATOMIC_RELAXED,
                                         __HIP_MEMORY_SCOPE_AGENT);
    return __uint_as_float(u);
}
__device__ __forceinline__ void astore(float* p, float v) {
    __hip_atomic_store((unsigned*)p, __float_as_uint(v), __ATOMIC_RELAXED,
                       __HIP_MEMORY_SCOPE_AGENT);
}
// 16-byte coherent load: same sc0+sc1 (device-scope, L1/L2-bypassing) path as
// the scalar atomic load, but 4x fewer coherence-point transactions.
__device__ __forceinline__ f32x4 aload4(const float* p) {
    f32x4 v;
    asm volatile("global_load_dwordx4 %0, %1, off sc0 sc1\n\t"
                 "s_waitcnt vmcnt(0)"
                 : "=v"(v) : "v"(p) : "memory");
    return v;
}

// Relaxed spin on a per-producer flag slot (distinct cacheline per producer).
__device__ __forceinline__ void wait_flag(const unsigned* f, unsigned target) {
    while (__hip_atomic_load(f, __ATOMIC_RELAXED, __HIP_MEMORY_SCOPE_AGENT) < target) {
        __builtin_amdgcn_s_sleep(2);
    }
}

// ---------------------------------------------------------------------------
// att1[b,p,a] = enc[b,p,:] @ W_enc_att[:,a] + b_enc_att[a]
// (block 0 also zeroes the flag slots for the fused kernel — per-launch reset)
// ---------------------------------------------------------------------------
__global__ void att1_kernel(const float* __restrict__ enc,
                            const float* __restrict__ W,
                            const float* __restrict__ bias,
                            float* __restrict__ att1,
                            unsigned* __restrict__ flags) {
    const int tid = threadIdx.x;
    if (blockIdx.x == 0) {
        for (int i = tid; i < NFLAGS; i += 256)
            __hip_atomic_store(flags + i, 0u, __ATOMIC_RELAXED, __HIP_MEMORY_SCOPE_AGENT);
    }
    __shared__ float xs[8][DENC];
    const int r0 = blockIdx.x * 8;
    #pragma unroll
    for (int bi = 0; bi < 8; ++bi)
        xs[bi][tid] = enc[(size_t)(r0 + bi) * DENC + tid];
    __syncthreads();
    float acc[8];
    const float bv = bias[tid];
    #pragma unroll
    for (int bi = 0; bi < 8; ++bi) acc[bi] = bv;
    #pragma unroll 8
    for (int k = 0; k < DENC; ++k) {
        const float w = W[k * AA + tid];
        #pragma unroll
        for (int bi = 0; bi < 8; ++bi) acc[bi] += xs[bi][k] * w;
    }
    #pragma unroll
    for (int bi = 0; bi < 8; ++bi)
        att1[(size_t)(r0 + bi) * AA + tid] = acc[bi];
}

// ---------------------------------------------------------------------------
// Epre[m, j] = emb[captions[b,t]] @ W_ih[0:512, j] + b_ih[j] + b_hh[j]
// ---------------------------------------------------------------------------
__global__ void epre_kernel(const int* __restrict__ captions,
                            const float* __restrict__ emb,
                            const float* __restrict__ Wih,
                            const float* __restrict__ bih,
                            const float* __restrict__ bhh,
                            float* __restrict__ Epre) {
    __shared__ float xs[8][EE];
    const int tid = threadIdx.x;
    const int jc = blockIdx.x;     // 0..7
    const int mg = blockIdx.y;     // 0..79
    const int j = jc * 256 + tid;

    #pragma unroll
    for (int i = 0; i < 8; ++i) {
        const int m = mg * 8 + i;
        const int t = m >> 5, b = m & 31;
        const int cap = captions[b * TT + t];
        const float* erow = emb + (size_t)cap * EE;
        xs[i][tid]       = erow[tid];
        xs[i][tid + 256] = erow[tid + 256];
    }
    __syncthreads();

    float acc[8];
    const float bv = bih[j] + bhh[j];
    #pragma unroll
    for (int i = 0; i < 8; ++i) acc[i] = bv;
    #pragma unroll 8
    for (int k = 0; k < EE; ++k) {
        const float w = Wih[(size_t)k * G4 + j];
        #pragma unroll
        for (int i = 0; i < 8; ++i) acc[i] += xs[i][k] * w;
    }
    #pragma unroll
    for (int i = 0; i < 8; ++i)
        Epre[(size_t)(mg * 8 + i) * G4 + j] = acc[i];
}

// ---------------------------------------------------------------------------
// One-time weight repack for the fused gates GEMM.
// Wpk[jc][k][cl] = (k < 256) ? Wih[512+k][col] : Whh[k-256][col]
//   where col = (cl>>4)*512 + jc*16 + (cl&15),  jc=0..31, k=0..767, cl=0..63.
// ---------------------------------------------------------------------------
__global__ void pack_w_kernel(const float* __restrict__ Wih,
                              const float* __restrict__ Whh,
                              float* __restrict__ Wpk) {
    const int jc = blockIdx.x;     // 0..31
    const int tid = threadIdx.x;   // 0..255
    float* dst = Wpk + (size_t)jc * 768 * 64;
    for (int i = tid; i < 768 * 64; i += 256) {
        const int k = i >> 6, cl = i & 63;
        const int col = ((cl >> 4) * 512) + jc * 16 + (cl & 15);
        const float v = (k < 256) ? Wih[(size_t)(512 + k) * G4 + col]
                                  : Whh[(size_t)(k - 256) * G4 + col];
        dst[i] = v;
    }
}

// ---------------------------------------------------------------------------
// FUSED persistent time-loop kernel: 256 blocks x 1024 threads, cooperative.
// Per-block flags, relaxed; payload via coherent loads/stores (x4-widened).
//   cflag[b]   (b=0..31) : attention block b publishes ctxb(t)  -> value t+1
//   gflag[bid] (0..255)  : gates block publishes its h(t) slice -> value t+1
// __syncthreads() before each flag store drains vmcnt in every wave, so
// payload stores are globally performed before the flag becomes visible.
// ---------------------------------------------------------------------------
__global__ __launch_bounds__(1024) void fused_loop_kernel(
        const float* __restrict__ att1,
        const float* __restrict__ enc,
        const float* __restrict__ Wda,
        const float* __restrict__ bda,
        const float* __restrict__ Wfull,
        const float* __restrict__ bfull,
        const float* __restrict__ Wpk,
        const float* __restrict__ Epre,
        float* __restrict__ hbuf,        // [2][32][512]
        float* __restrict__ ctxb,        // [32][256]
        float* __restrict__ Hall,        // [640][512]
        unsigned short* __restrict__ Ah,
        unsigned short* __restrict__ Al,
        unsigned* flags,
        int write_split) {
    const int bid = blockIdx.x;        // 0..255
    const int tid = threadIdx.x;       // 0..1023
    const int jc = bid & 31;           // h-dim slice (same-jc blocks share an XCD)
    const int bg = bid >> 5;           // 0..7 (4 batches each)

    unsigned* cflag = flags;           // [32] slots, stride 32 uints (128B)
    unsigned* gflag = flags + 32 * 32; // [256] slots, stride 32 uints

    __shared__ float h_s[HH];
    __shared__ float part[4][256];
    __shared__ float att2_s[AA];
    __shared__ float e_s[256];
    __shared__ float red_s[256];
    __shared__ float xs[4][768];
    __shared__ float gred[256];

    float c_reg = 0.f;                 // per-thread c state (threads tid<64 use it)

    for (int t = 0; t < TT; ++t) {
        float* hprev = hbuf + ((t + 1) & 1) * 16384;   // h(t-1)

        // ---------------- attention phase (blocks 0..31) ----------------
        if (bid < 32) {
            const int b = bid;
            if (t > 0) {
                // wait for h(t-1)[b] = all 32 gates blocks of group b>>2
                if (tid < 32) wait_flag(gflag + ((b >> 2) * 32 + tid) * 32, (unsigned)t);
                asm volatile("" ::: "memory");
                __syncthreads();
            }
            if (tid < 128) {
                f32x4 v;
                if (t > 0) v = aload4(&hprev[b * HH + tid * 4]);
                else       v = (f32x4){0.f, 0.f, 0.f, 0.f};
                *(f32x4*)&h_s[tid * 4] = v;
            }
            __syncthreads();
            // att2 = h @ Wda + bda (4-way split-K)
            {
                const int q = tid >> 8, col = tid & 255;
                const float* W = Wda + (size_t)(q * 128) * AA + col;
                const float* hh = h_s + q * 128;
                float acc = 0.f;
                #pragma unroll 16
                for (int k = 0; k < 128; ++k) acc += hh[k] * W[(size_t)k * AA];
                part[q][col] = acc;
            }
            __syncthreads();
            if (tid < 256)
                att2_s[tid] = part[0][tid] + part[1][tid] + part[2][tid] + part[3][tid] + bda[tid];
            __syncthreads();
            // e[p], one wave per p
            {
                const int wave = tid >> 6, lane = tid & 63;
                const float bf0 = bfull[0];
                for (int p = wave; p < PP; p += 16) {
                    const float* row = att1 + ((size_t)b * PP + p) * AA;
                    float s = 0.f;
                    #pragma unroll
                    for (int q = 0; q < 4; ++q) {
                        const int a = lane + q * 64;
                        s += fast_tanh(row[a] + att2_s[a]) * Wfull[a];
                    }
                    #pragma unroll
                    for (int off = 32; off > 0; off >>= 1) s += __shfl_down(s, off, 64);
                    if (lane == 0) e_s[p] = s + bf0;
                }
            }
            __syncthreads();
            // softmax over p — shuffle-based, 3 barriers
            {
                const int lane = tid & 63, wv = tid >> 6;
                const float val = (tid < PP) ? e_s[tid] : -3.4e38f;
                float m = val;
                if (tid < 256) {
                    #pragma unroll
                    for (int off = 32; off > 0; off >>= 1) m = fmaxf(m, __shfl_down(m, off, 64));
                    if (lane == 0) red_s[wv] = m;
                }
                __syncthreads();
                const float mx = fmaxf(fmaxf(red_s[0], red_s[1]), fmaxf(red_s[2], red_s[3]));
                const float ex = (tid < PP) ? __expf(val - mx) : 0.f;
                float sm = ex;
                if (tid < 256) {
                    #pragma unroll
                    for (int off = 32; off > 0; off >>= 1) sm += __shfl_down(sm, off, 64);
                    if (lane == 0) red_s[4 + wv] = sm;
                }
                __syncthreads();
                const float inv = 1.f / (red_s[4] + red_s[5] + red_s[6] + red_s[7]);
                if (tid < 256) e_s[tid] = ex * inv;   // alpha (0 for p >= 196)
            }
            __syncthreads();
            // context = alpha @ enc
            {
                const int q = tid >> 8, col = tid & 255;
                const float* erow = enc + (size_t)b * PP * DENC + col;
                float acc = 0.f;
                const int p0 = q * 49;
                #pragma unroll 7
                for (int p = p0; p < p0 + 49; ++p) acc += e_s[p] * erow[(size_t)p * DENC];
                part[q][col] = acc;
            }
            __syncthreads();
            if (tid < 256)
                astore(&ctxb[b * DENC + tid],
                       part[0][tid] + part[1][tid] + part[2][tid] + part[3][tid]);
            __syncthreads();   // drains vmcnt in all waves -> payload performed
            if (tid == 0)
                __hip_atomic_store(cflag + b * 32, (unsigned)(t + 1),
                                   __ATOMIC_RELAXED, __HIP_MEMORY_SCOPE_AGENT);
        }

        // ---------------- gates + pointwise phase (all blocks) ----------------
        // Prefetch Epre (depends only on t) BEFORE the wait — hides its latency.
        float epre_v = 0.f;
        if (tid < 256) {
            const int bl = tid >> 6, cl = tid & 63;
            const int b = bg * 4 + bl;
            const int col = ((cl >> 4) * 512) + jc * 16 + (cl & 15);
            epre_v = Epre[(size_t)(t * BB + b) * G4 + col];
        }
        // wait for ctxb of this block's 4 batches
        if (tid < 4) wait_flag(cflag + (bg * 4 + tid) * 32, (unsigned)(t + 1));
        asm volatile("" ::: "memory");
        __syncthreads();

        // stage x = [context(256), h(512)] for 4 batches (coherent x4 loads)
        if (tid < 768) {
            const int bi = tid / 192;           // 0..3
            const int k = (tid - bi * 192) * 4; // 0..764 step 4
            const int b = bg * 4 + bi;
            f32x4 v;
            if (k < 256)      v = aload4(&ctxb[b * DENC + k]);
            else if (t > 0)   v = aload4(&hprev[b * HH + (k - 256)]);
            else              v = (f32x4){0.f, 0.f, 0.f, 0.f};
            *(f32x4*)&xs[bi][k] = v;
        }
        __syncthreads();
        {
            const int kq = tid >> 8;            // 0..3, wave-uniform
            const int r = tid & 255;
            const int bl = r >> 6;              // local batch 0..3
            const int cl = r & 63;              // g*16 + hdl
            const float* xr = xs[bl] + kq * 192;
            const float* Wp = Wpk + ((size_t)jc * 768 + kq * 192) * 64 + cl;
            float acc = 0.f;
            #pragma unroll 16
            for (int k = 0; k < 192; ++k) acc += xr[k] * Wp[(size_t)k * 64];
            part[kq][r] = acc;
        }
        __syncthreads();
        if (tid < 256) {
            gred[tid] = part[0][tid] + part[1][tid] + part[2][tid] + part[3][tid] + epre_v;
        }
        __syncthreads();
        if (tid < 64) {
            const int bl = tid >> 4;            // 0..3
            const int hdl = tid & 15;
            const float gi = gred[bl * 64 +  0 + hdl];
            const float gf = gred[bl * 64 + 16 + hdl];
            const float gg = gred[bl * 64 + 32 + hdl];
            const float go = gred[bl * 64 + 48 + hdl];
            const float cn = fast_sigmoid(gf) * c_reg + fast_sigmoid(gi) * fast_tanh(gg);
            const float hn = fast_sigmoid(go) * fast_tanh(cn);
            c_reg = cn;
            const int b = bg * 4 + bl;
            const int hd = jc * 16 + hdl;
            astore(&hbuf[(t & 1) * 16384 + b * HH + hd], hn);   // coherent publish
            const size_t mi = (size_t)(t * BB + b) * HH + hd;
            Hall[mi] = hn;
            if (write_split) {
                unsigned short hh_, ll_;
                split_bf16(hn, hh_, ll_);
                Ah[mi] = hh_;
                Al[mi] = ll_;
            }
        }
        if (t < TT - 1) {
            __syncthreads();   // drains vmcnt -> h publish performed
            if (tid == 0)
                __hip_atomic_store(gflag + bid * 32, (unsigned)(t + 1),
                                   __ATOMIC_RELAXED, __HIP_MEMORY_SCOPE_AGENT);
        }
    }
}

// ---------------------------------------------------------------------------
// FALLBACK per-timestep kernels (used only if cooperative launch fails)
// ---------------------------------------------------------------------------
__global__ __launch_bounds__(1024) void attn_step_kernel(
        int t,
        const float* __restrict__ att1,
        const float* __restrict__ enc,
        float* __restrict__ Hall,
        float* __restrict__ cbuf,
        const float* __restrict__ gates,
        float* __restrict__ context,
        const float* __restrict__ Wda,
        const float* __restrict__ bda,
        const float* __restrict__ Wfull,
        const float* __restrict__ bfull) {
    __shared__ float h_s[HH];
    __shared__ float part[4][256];
    __shared__ float att2_s[AA];
    __shared__ float e_s[256];
    __shared__ float red_s[256];
    const int b = blockIdx.x;
    const int tid = threadIdx.x;

    if (tid < 512) {
        if (t == 0) {
            h_s[tid] = 0.f;
            cbuf[b * HH + tid] = 0.f;
        } else {
            const float* g = gates + b * G4;
            const float gi = g[tid];
            const float gf = g[HH + tid];
            const float gg = g[2 * HH + tid];
            const float go = g[3 * HH + tid];
            const float cp = cbuf[b * HH + tid];
            const float cn = fast_sigmoid(gf) * cp + fast_sigmoid(gi) * fast_tanh(gg);
            const float hn = fast_sigmoid(go) * fast_tanh(cn);
            cbuf[b * HH + tid] = cn;
            Hall[(size_t)(t - 1) * BH + b * HH + tid] = hn;
            h_s[tid] = hn;
        }
    }
    __syncthreads();

    {
        const int q = tid >> 8, col = tid & 255;
        const float* W = Wda + (size_t)(q * 128) * AA + col;
        const float* hh = h_s + q * 128;
        float acc = 0.f;
        #pragma unroll 16
        for (int k = 0; k < 128; ++k) acc += hh[k] * W[(size_t)k * AA];
        part[q][col] = acc;
    }
    __syncthreads();
    if (tid < 256)
        att2_s[tid] = part[0][tid] + part[1][tid] + part[2][tid] + part[3][tid] + bda[tid];
    __syncthreads();

    {
        const int wave = tid >> 6, lane = tid & 63;
        const float bf0 = bfull[0];
        for (int p = wave; p < PP; p += 16) {
            const float* row = att1 + ((size_t)b * PP + p) * AA;
            float s = 0.f;
            #pragma unroll
            for (int q = 0; q < 4; ++q) {
                const int a = lane + q * 64;
                s += fast_tanh(row[a] + att2_s[a]) * Wfull[a];
            }
            #pragma unroll
            for (int off = 32; off > 0; off >>= 1) s += __shfl_down(s, off, 64);
            if (lane == 0) e_s[p] = s + bf0;
        }
    }
    __syncthreads();

    const float val = (tid < PP) ? e_s[tid] : -3.4e38f;
    if (tid < 256) red_s[tid] = val;
    __syncthreads();
    #pragma unroll
    for (int s = 128; s > 0; s >>= 1) {
        if (tid < s) red_s[tid] = fmaxf(red_s[tid], red_s[tid + s]);
        __syncthreads();
    }
    const float mx = red_s[0];
    __syncthreads();
    const float ex = (tid < PP) ? __expf(val - mx) : 0.f;
    if (tid < 256) red_s[tid] = ex;
    __syncthreads();
    #pragma unroll
    for (int s = 128; s > 0; s >>= 1) {
        if (tid < s) red_s[tid] += red_s[tid + s];
        __syncthreads();
    }
    const float inv = 1.f / red_s[0];
    __syncthreads();
    if (tid < 256) e_s[tid] = ex * inv;
    __syncthreads();

    {
        const int q = tid >> 8, col = tid & 255;
        const float* erow = enc + (size_t)b * PP * DENC + col;
        float acc = 0.f;
        const int p0 = q * 49;
        #pragma unroll 7
        for (int p = p0; p < p0 + 49; ++p) acc += e_s[p] * erow[(size_t)p * DENC];
        part[q][col] = acc;
    }
    __syncthreads();
    if (tid < 256)
        context[b * DENC + tid] = part[0][tid] + part[1][tid] + part[2][tid] + part[3][tid];
}

__global__ __launch_bounds__(1024) void gates_kernel(
        int t,
        const float* __restrict__ context,
        const float* __restrict__ Hall,
        const float* __restrict__ Epre,
        const float* __restrict__ Wih,
        const float* __restrict__ Whh,
        float* __restrict__ gates) {
    __shared__ float xs[4][768];
    __shared__ float part[4][256];
    const int tid = threadIdx.x;
    const int jc = blockIdx.x;
    const int bg = blockIdx.y;

    for (int idx = tid; idx < 4 * 768; idx += 1024) {
        const int bi = idx / 768;
        const int k = idx - bi * 768;
        const int b = bg * 4 + bi;
        float v;
        if (k < 256) v = context[b * DENC + k];
        else v = (t > 0) ? Hall[(size_t)(t - 1) * BH + b * HH + (k - 256)] : 0.f;
        xs[bi][k] = v;
    }
    __syncthreads();

    const int kq = tid >> 8;
    const int r = tid & 255;
    const int jl = r & 63, bl = r >> 6;
    const int j = jc * 64 + jl;
    const float* xrow = xs[bl];

    float acc = 0.f;
    if (kq == 0) {
        const float* W1 = Wih + (size_t)512 * G4 + j;
        #pragma unroll 16
        for (int k = 0; k < 192; ++k) acc += xrow[k] * W1[(size_t)k * G4];
    } else if (kq == 1) {
        const float* W1 = Wih + (size_t)704 * G4 + j;
        #pragma unroll 16
        for (int k = 0; k < 64; ++k) acc += xrow[192 + k] * W1[(size_t)k * G4];
        const float* W2 = Whh + j;
        #pragma unroll 16
        for (int k = 0; k < 128; ++k) acc += xrow[256 + k] * W2[(size_t)k * G4];
    } else if (kq == 2) {
        const float* W2 = Whh + (size_t)128 * G4 + j;
        #pragma unroll 16
        for (int k = 0; k < 192; ++k) acc += xrow[384 + k] * W2[(size_t)k * G4];
    } else {
        const float* W2 = Whh + (size_t)320 * G4 + j;
        #pragma unroll 16
        for (int k = 0; k < 192; ++k) acc += xrow[576 + k] * W2[(size_t)k * G4];
    }
    part[kq][r] = acc;
    __syncthreads();

    if (tid < 256) {
        const int b = bg * 4 + bl;
        gates[(size_t)b * G4 + j] = part[0][tid] + part[1][tid] + part[2][tid] + part[3][tid]
                                  + Epre[(size_t)(t * BB + b) * G4 + j];
    }
}

__global__ void final_update_kernel(const float* __restrict__ gates,
                                    const float* __restrict__ cbuf,
                                    float* __restrict__ Hall) {
    const int idx = blockIdx.x * 256 + threadIdx.x;
    const int b = idx >> 9, hi = idx & 511;
    const float* g = gates + b * G4;
    const float gi = g[hi];
    const float gf = g[HH + hi];
    const float gg = g[2 * HH + hi];
    const float go = g[3 * HH + hi];
    const float cp = cbuf[idx];
    const float cn = fast_sigmoid(gf) * cp + fast_sigmoid(gi) * fast_tanh(gg);
    const float hn = fast_sigmoid(go) * fast_tanh(cn);
    Hall[(size_t)(TT - 1) * BH + idx] = hn;
}

__global__ void split_hall_kernel(const float* __restrict__ Hall,
                                  unsigned short* __restrict__ Ah,
                                  unsigned short* __restrict__ Al) {
    const int idx = blockIdx.x * 256 + threadIdx.x;
    unsigned short h, l;
    split_bf16(Hall[idx], h, l);
    Ah[idx] = h; Al[idx] = l;
}

// ---------------------------------------------------------------------------
// Transpose + split Wfc[k][v] -> Wt_h/Wt_l[v][k], v padded to VPAD (zero-fill).
// ---------------------------------------------------------------------------
__global__ void split_wfc_kernel(const float* __restrict__ Wfc,
                                 unsigned short* __restrict__ Wt_h,
                                 unsigned short* __restrict__ Wt_l) {
    __shared__ unsigned short th[64][66];
    __shared__ unsigned short tl[64][66];
    const int tid = threadIdx.x;
    const int k0 = blockIdx.x * 64;
    const int v0 = blockIdx.y * 64;

    const int c = tid & 63, r0 = tid >> 6;
    #pragma unroll
    for (int i = 0; i < 16; ++i) {
        const int r = r0 + i * 4;
        const int v = v0 + c;
        const float x = (v < VV) ? Wfc[(size_t)(k0 + r) * VV + v] : 0.f;
        unsigned short h, l;
        split_bf16(x, h, l);
        th[r][c] = h; tl[r][c] = l;
    }
    __syncthreads();

    const int v = tid >> 2, q = tid & 3;
    short8 oh0, oh1, ol0, ol1;
    #pragma unroll
    for (int i = 0; i < 8; ++i) {
        oh0[i] = (short)th[q * 16 + i][v];
        oh1[i] = (short)th[q * 16 + 8 + i][v];
        ol0[i] = (short)tl[q * 16 + i][v];
        ol1[i] = (short)tl[q * 16 + 8 + i][v];
    }
    unsigned short* dh = Wt_h + (size_t)(v0 + v) * HH + k0 + q * 16;
    unsigned short* dl = Wt_l + (size_t)(v0 + v) * HH + k0 + q * 16;
    *(short8*)(dh) = oh0; *(short8*)(dh + 8) = oh1;
    *(short8*)(dl) = ol0; *(short8*)(dl + 8) = ol1;
}

// ---------------------------------------------------------------------------
// Output projection, pre-split path: pure-copy staging, bf16x3 MFMA.
// ---------------------------------------------------------------------------
#define LDK 40   // padded LDS row length in bf16 units

__global__ __launch_bounds__(256) void gemm_out_mfma_pre(
        const unsigned short* __restrict__ Ah,
        const unsigned short* __restrict__ Al,
        const unsigned short* __restrict__ Wt_h,
        const unsigned short* __restrict__ Wt_l,
        const float* __restrict__ bfc,
        float* __restrict__ out) {
    __shared__ unsigned short As_h[128 * LDK];
    __shared__ unsigned short As_l[128 * LDK];
    __shared__ unsigned short Bs_h[128 * LDK];
    __shared__ unsigned short Bs_l[128 * LDK];

    const int tid = threadIdx.x;
    const int m0 = blockIdx.x * 128;
    const int v0 = blockIdx.y * 128;

    const int wave = tid >> 6, lane = tid & 63;
    const int wm = wave & 1, wn = wave >> 1;
    const int row16 = lane & 15, quad = lane >> 4;

    const int sn = tid & 127;
    const int skq = tid >> 7;

    f32x4 acc[4][4] = {};

    #pragma unroll 1
    for (int k0 = 0; k0 < HH; k0 += 32) {
        {
            const size_t src = (size_t)(m0 + sn) * HH + k0 + skq * 16;
            const short8 h0 = *(const short8*)(Ah + src);
            const short8 h1 = *(const short8*)(Ah + src + 8);
            const short8 l0 = *(const short8*)(Al + src);
            const short8 l1 = *(const short8*)(Al + src + 8);
            unsigned short* dh = &As_h[sn * LDK + skq * 16];
            unsigned short* dl = &As_l[sn * LDK + skq * 16];
            *(short8*)(dh) = h0; *(short8*)(dh + 8) = h1;
            *(short8*)(dl) = l0; *(short8*)(dl + 8) = l1;
        }
        {
            const size_t src = (size_t)(v0 + sn) * HH + k0 + skq * 16;
            const short8 h0 = *(const short8*)(Wt_h + src);
            const short8 h1 = *(const short8*)(Wt_h + src + 8);
            const short8 l0 = *(const short8*)(Wt_l + src);
            const short8 l1 = *(const short8*)(Wt_l + src + 8);
            unsigned short* dh = &Bs_h[sn * LDK + skq * 16];
            unsigned short* dl = &Bs_l[sn * LDK + skq * 16];
            *(short8*)(dh) = h0; *(short8*)(dh + 8) = h1;
            *(short8*)(dl) = l0; *(short8*)(dl + 8) = l1;
        }
        __syncthreads();

        short8 ah[4], al[4], bh[4], bl[4];
        #pragma unroll
        for (int mi = 0; mi < 4; ++mi) {
            const int off = (wm * 64 + mi * 16 + row16) * LDK + quad * 8;
            ah[mi] = *(const short8*)&As_h[off];
            al[mi] = *(const short8*)&As_l[off];
        }
        #pragma unroll
        for (int ni = 0; ni < 4; ++ni) {
            const int off = (wn * 64 + ni * 16 + row16) * LDK + quad * 8;
            bh[ni] = *(const short8*)&Bs_h[off];
            bl[ni] = *(const short8*)&Bs_l[off];
        }
        #pragma unroll
        for (int mi = 0; mi < 4; ++mi) {
            #pragma unroll
            for (int ni = 0; ni < 4; ++ni) {
                acc[mi][ni] = __builtin_amdgcn_mfma_f32_16x16x32_bf16(
                    ah[mi], bh[ni], acc[mi][ni], 0, 0, 0);
                acc[mi][ni] = __builtin_amdgcn_mfma_f32_16x16x32_bf16(
                    ah[mi], bl[ni], acc[mi][ni], 0, 0, 0);
                acc[mi][ni] = __builtin_amdgcn_mfma_f32_16x16x32_bf16(
                    al[mi], bh[ni], acc[mi][ni], 0, 0, 0);
            }
        }
        __syncthreads();
    }

    #pragma unroll
    for (int ni = 0; ni < 4; ++ni) {
        const int v = v0 + wn * 64 + ni * 16 + row16;
        if (v >= VV) continue;
        const float bias = bfc[v];
        #pragma unroll
        for (int mi = 0; mi < 4; ++mi) {
            const int mbase = m0 + wm * 64 + mi * 16 + quad * 4;
            #pragma unroll
            for (int r = 0; r < 4; ++r) {
                const int m = mbase + r;
                const int t_idx = m >> 5;
                const int b_idx = m & 31;
                out[((size_t)b_idx * TT + t_idx) * VV + v] = acc[mi][ni][r] + bias;
            }
        }
    }
}

// ---------------------------------------------------------------------------
// Fallback gemm (in-kernel split) — used when ws is too small for tables.
// ---------------------------------------------------------------------------
__global__ __launch_bounds__(256) void gemm_out_mfma_fb(
        const float* __restrict__ Hall,
        const float* __restrict__ Wfc,
        const float* __restrict__ bfc,
        float* __restrict__ out) {
    __shared__ unsigned short As_h[128 * LDK];
    __shared__ unsigned short As_l[128 * LDK];
    __shared__ unsigned short Bs_h[128 * LDK];
    __shared__ unsigned short Bs_l[128 * LDK];

    const int tid = threadIdx.x;
    const int m0 = blockIdx.x * 128;
    const int v0 = blockIdx.y * 128;

    const int wave = tid >> 6, lane = tid & 63;
    const int wm = wave & 1, wn = wave >> 1;
    const int row16 = lane & 15, quad = lane >> 4;

    const int sn = tid & 127;
    const int skq = tid >> 7;

    f32x4 acc[4][4] = {};

    #pragma unroll 1
    for (int k0 = 0; k0 < HH; k0 += 32) {
        {
            const float* asrc = Hall + (size_t)(m0 + sn) * HH + k0 + skq * 16;
            short8 h0, h1, l0, l1;
            #pragma unroll
            for (int i = 0; i < 16; i += 4) {
                const float4 v = *reinterpret_cast<const float4*>(asrc + i);
                const float vv[4] = {v.x, v.y, v.z, v.w};
                #pragma unroll
                for (int jj = 0; jj < 4; ++jj) {
                    unsigned short hb, lb;
                    split_bf16(vv[jj], hb, lb);
                    const int e = i + jj;
                    if (e < 8) { h0[e] = (short)hb; l0[e] = (short)lb; }
                    else       { h1[e - 8] = (short)hb; l1[e - 8] = (short)lb; }
                }
            }
            unsigned short* dh = &As_h[sn * LDK + skq * 16];
            unsigned short* dl = &As_l[sn * LDK + skq * 16];
            *(short8*)(dh) = h0; *(short8*)(dh + 8) = h1;
            *(short8*)(dl) = l0; *(short8*)(dl + 8) = l1;
        }
        {
            const int vcol = v0 + sn;
            const bool ok = vcol < VV;
            const float* bsrc = Wfc + (size_t)(k0 + skq * 16) * VV + vcol;
            short8 h0, h1, l0, l1;
            #pragma unroll
            for (int i = 0; i < 16; ++i) {
                const float x = ok ? bsrc[(size_t)i * VV] : 0.f;
                unsigned short hb, lb;
                split_bf16(x, hb, lb);
                if (i < 8) { h0[i] = (short)hb; l0[i] = (short)lb; }
                else       { h1[i - 8] = (short)hb; l1[i - 8] = (short)lb; }
            }
            unsigned short* dh = &Bs_h[sn * LDK + skq * 16];
            unsigned short* dl = &Bs_l[sn * LDK + skq * 16];
            *(short8*)(dh) = h0; *(short8*)(dh + 8) = h1;
            *(short8*)(dl) = l0; *(short8*)(dl + 8) = l1;
        }
        __syncthreads();

        short8 ah[4], al[4], bh[4], bl[4];
        #pragma unroll
        for (int mi = 0; mi < 4; ++mi) {
            const int off = (wm * 64 + mi * 16 + row16) * LDK + quad * 8;
            ah[mi] = *(const short8*)&As_h[off];
            al[mi] = *(const short8*)&As_l[off];
        }
        #pragma unroll
        for (int ni = 0; ni < 4; ++ni) {
            const int off = (wn * 64 + ni * 16 + row16) * LDK + quad * 8;
            bh[ni] = *(const short8*)&Bs_h[off];
            bl[ni] = *(const short8*)&Bs_l[off];
        }
        #pragma unroll
        for (int mi = 0; mi < 4; ++mi) {
            #pragma unroll
            for (int ni = 0; ni < 4; ++ni) {
                acc[mi][ni] = __builtin_amdgcn_mfma_f32_16x16x32_bf16(
                    ah[mi], bh[ni], acc[mi][ni], 0, 0, 0);
                acc[mi][ni] = __builtin_amdgcn_mfma_f32_16x16x32_bf16(
                    ah[mi], bl[ni], acc[mi][ni], 0, 0, 0);
                acc[mi][ni] = __builtin_amdgcn_mfma_f32_16x16x32_bf16(
                    al[mi], bh[ni], acc[mi][ni], 0, 0, 0);
            }
        }
        __syncthreads();
    }

    #pragma unroll
    for (int ni = 0; ni < 4; ++ni) {
        const int v = v0 + wn * 64 + ni * 16 + row16;
        if (v >= VV) continue;
        const float bias = bfc[v];
        #pragma unroll
        for (int mi = 0; mi < 4; ++mi) {
            const int mbase = m0 + wm * 64 + mi * 16 + quad * 4;
            #pragma unroll
            for (int r = 0; r < 4; ++r) {
                const int m = mbase + r;
                const int t_idx = m >> 5;
                const int b_idx = m & 31;
                out[((size_t)b_idx * TT + t_idx) * VV + v] = acc[mi][ni][r] + bias;
            }
        }
    }
}

// ---------------------------------------------------------------------------
extern "C" void kernel_launch(void* const* d_in, const int* in_sizes, int n_in,
                              void* d_out, int out_size, void* d_ws, size_t ws_size,
                              hipStream_t stream) {
    const float* enc      = (const float*)d_in[0];
    const int*   captions = (const int*)  d_in[1];
    const float* Wea      = (const float*)d_in[2];
    const float* bea      = (const float*)d_in[3];
    const float* Wda      = (const float*)d_in[4];
    const float* bda      = (const float*)d_in[5];
    const float* Wfull    = (const float*)d_in[6];
    const float* bfull    = (const float*)d_in[7];
    const float* emb      = (const float*)d_in[8];
    const float* Wih      = (const float*)d_in[9];
    const float* bih      = (const float*)d_in[10];
    const float* Whh      = (const float*)d_in[11];
    const float* bhh      = (const float*)d_in[12];
    const float* Wfc      = (const float*)d_in[13];
    const float* bfc      = (const float*)d_in[14];
    float* out = (float*)d_out;

    float* ws   = (float*)d_ws;
    float* att1 = ws;                          // 1,605,632 f
    float* Hall = att1 + 1605632;              //   327,680 f
    float* Epre = Hall + 327680;               // 1,310,720 f
    float* hbuf = Epre + 1310720;              //    32,768 f (2x double-buffered h)
    float* ctxb = hbuf + 32768;                //     8,192 f
    unsigned* flags = (unsigned*)(ctxb + 8192);//     9,216 u (288 x 32-uint slots)
    float* Wpk  = ctxb + 8192 + NFLAGS;        // 1,572,864 f (packed gate weights)
    float* tail = Wpk + 1572864;               // bf16 tables start here
    unsigned short* Ah   = (unsigned short*)tail;              // 640*512
    unsigned short* Al   = Ah + 640 * 512;
    unsigned short* Wt_h = Al + 640 * 512;                     // VPAD*512
    unsigned short* Wt_l = Wt_h + (size_t)VPAD * HH;
    const size_t need_bytes =
        (size_t)(4867072) * 4 +                       // fp32 scratch (+flags+Wpk)
        (size_t)(2 * 640 * 512) * 2 +                 // Ah/Al
        (size_t)(2 * (size_t)VPAD * HH) * 2;          // Wt_h/Wt_l
    const bool pre = ws_size >= need_bytes;

    att1_kernel<<<dim3(784), dim3(256), 0, stream>>>(enc, Wea, bea, att1, flags);
    epre_kernel<<<dim3(8, 80), dim3(256), 0, stream>>>(captions, emb, Wih, bih, bhh, Epre);
    pack_w_kernel<<<dim3(32), dim3(256), 0, stream>>>(Wih, Whh, Wpk);
    if (pre) {
        split_wfc_kernel<<<dim3(8, VPAD / 64), dim3(256), 0, stream>>>(Wfc, Wt_h, Wt_l);
    }

    int write_split = pre ? 1 : 0;
    void* cargs[] = {
        (void*)&att1, (void*)&enc, (void*)&Wda, (void*)&bda, (void*)&Wfull, (void*)&bfull,
        (void*)&Wpk, (void*)&Epre, (void*)&hbuf, (void*)&ctxb, (void*)&Hall,
        (void*)&Ah, (void*)&Al, (void*)&flags, (void*)&write_split };
    hipError_t cerr = hipLaunchCooperativeKernel(fused_loop_kernel,
                                                 dim3(NBLK), dim3(1024),
                                                 cargs, 0, stream);
    if (cerr != hipSuccess) {
        // Fallback: old per-step loop. Scratch aliased over the Ah/Al table
        // region (written only after the loop completes).
        float* cbuf    = (float*)tail;        // 16,384 f
        float* context = cbuf + 16384;        //  8,192 f
        float* gates   = context + 8192;      // 65,536 f
        for (int t = 0; t < TT; ++t) {
            attn_step_kernel<<<dim3(BB), dim3(1024), 0, stream>>>(
                t, att1, enc, Hall, cbuf, gates, context, Wda, bda, Wfull, bfull);
            gates_kernel<<<dim3(32, 8), dim3(1024), 0, stream>>>(
                t, context, Hall, Epre, Wih, Whh, gates);
        }
        final_update_kernel<<<dim3(64), dim3(256), 0, stream>>>(gates, cbuf, Hall);
        if (pre) {
            split_hall_kernel<<<dim3(1280), dim3(256), 0, stream>>>(Hall, Ah, Al);
        }
    }

    if (pre) {
        gemm_out_mfma_pre<<<dim3(5, 235), dim3(256), 0, stream>>>(
            Ah, Al, Wt_h, Wt_l, bfc, out);
    } else {
        gemm_out_mfma_fb<<<dim3(5, 235), dim3(256), 0, stream>>>(Hall, Wfc, bfc, out);
    }
}